// Round 1
// baseline (1275.271 us; speedup 1.0000x reference)
//
#include <hip/hip_runtime.h>
#include <math.h>

#define B_    512
#define SQ_   49
#define SK_   50
#define DIMG_ 2048
#define DTXT_ 768
#define D_    512
#define H_    4
#define DH_   128

// output offsets (floats): score, attn_output, attn_weights, pi, pt
#define SCORE_OFF 0
#define AO_OFF    262144      // 512*512
#define AW_OFF    13107200    // + 512*49*512
#define PI_OFF    14361600    // + 512*49*50
#define PT_OFF    27206656    // + 512*49*512

typedef unsigned short bfbits;
typedef __attribute__((ext_vector_type(8))) short short8;
typedef __attribute__((ext_vector_type(4))) float floatx4;

static __device__ __forceinline__ bfbits f2bf(float f) {
    union { float f; unsigned u; } a; a.f = f;
    return (bfbits)((a.u + 0x7fffu + ((a.u >> 16) & 1u)) >> 16);
}
static __device__ __forceinline__ float bf2f(bfbits b) {
    union { unsigned u; float f; } a; a.u = ((unsigned)b) << 16;
    return a.f;
}
static __device__ __forceinline__ float gelu_exact(float x) {
    return 0.5f * x * (1.0f + erff(x * 0.70710678118654752f));
}

// ---------------------------------------------------------------------------
// Weight transpose+cast: W (K,N) fp32 -> Wt (N,K) bf16.  K,N % 32 == 0.
// ---------------------------------------------------------------------------
__global__ __launch_bounds__(256) void wcast_t(
    const float* __restrict__ W, bfbits* __restrict__ Wt, int K, int N)
{
    __shared__ float t[32][33];
    const int k0 = blockIdx.x * 32, n0 = blockIdx.y * 32;
    const int tx = threadIdx.x & 31, ty = threadIdx.x >> 5;  // 32 x 8
    #pragma unroll
    for (int i = 0; i < 32; i += 8)
        t[ty + i][tx] = W[(size_t)(k0 + ty + i) * N + n0 + tx];
    __syncthreads();
    #pragma unroll
    for (int i = 0; i < 32; i += 8)
        Wt[(size_t)(n0 + ty + i) * K + k0 + tx] = f2bf(t[tx][ty + i]);
}

// ---------------------------------------------------------------------------
// Image transpose+cast: img[b, k, s] fp32 -> A[(b*49+s), k] bf16 (K=2048)
// block = (k-tile of 64, b)
// ---------------------------------------------------------------------------
__global__ __launch_bounds__(256) void img_t(
    const float* __restrict__ img, bfbits* __restrict__ A)
{
    __shared__ float t[64][50];
    const int b = blockIdx.y, k0 = blockIdx.x * 64;
    const float* src = img + (size_t)b * (DIMG_ * SQ_) + (size_t)k0 * SQ_;
    for (int e = threadIdx.x; e < 64 * 49; e += 256) {
        int kl = e / 49, s = e - kl * 49;
        t[kl][s] = src[kl * 49 + s];
    }
    __syncthreads();
    bfbits* dst = A + (size_t)b * SQ_ * DIMG_ + k0;
    for (int e = threadIdx.x; e < 49 * 64; e += 256) {
        int s = e >> 6, kl = e & 63;
        dst[(size_t)s * DIMG_ + kl] = f2bf(t[kl][s]);
    }
}

// ---------------------------------------------------------------------------
// Flat fp32 -> bf16 cast, 4 elements/thread. n % 4 == 0.
// ---------------------------------------------------------------------------
__global__ __launch_bounds__(256) void cast4(
    const float* __restrict__ x, bfbits* __restrict__ y, int n4)
{
    int i = blockIdx.x * 256 + threadIdx.x;
    if (i < n4) {
        float4 v = ((const float4*)x)[i];
        ushort4 u;
        u.x = f2bf(v.x); u.y = f2bf(v.y); u.z = f2bf(v.z); u.w = f2bf(v.w);
        ((ushort4*)y)[i] = u;
    }
}

// ---------------------------------------------------------------------------
// bf16 MFMA GEMM: C[M,512] = A[M,K] @ Bt[512,K]^T + bias (+res fp32).
// 128x128 tile, BK=32, 4 waves (64x64 each, 4x4 MFMA grid), global_load_lds.
// M%128==0, K%32==0. res may alias Cf (element-wise read-then-write).
// GELU: Cb=gelu(v) bf16, Cf=v fp32. Else WBF: Cb=bf16(v). WF32: Cf=v.
// ---------------------------------------------------------------------------
template<bool RES, bool GELU, bool WF32, bool WBF>
__global__ __launch_bounds__(256) void gemm_bf16(
    const bfbits* __restrict__ A, const bfbits* __restrict__ Bt,
    const float* __restrict__ bias, const float* res,
    float* Cf, bfbits* __restrict__ Cb, int M, int K)
{
    constexpr int N = 512;
    __shared__ __attribute__((aligned(16))) bfbits As[128 * 32];
    __shared__ __attribute__((aligned(16))) bfbits Bs[128 * 32];
    const int tid  = threadIdx.x;
    const int wave = tid >> 6, lane = tid & 63;
    const int m0 = blockIdx.y * 128, n0 = blockIdx.x * 128;
    const int wm = (wave >> 1) * 64, wn = (wave & 1) * 64;
    const int lr = lane & 15, quad = lane >> 4;

    floatx4 acc[4][4];
    #pragma unroll
    for (int i = 0; i < 4; ++i)
        #pragma unroll
        for (int j = 0; j < 4; ++j) acc[i][j] = 0.0f;

    // per-lane source row/col offset for staging (chunk c: rows c*16+(lane>>2))
    const int srow = lane >> 2;            // 0..15
    const int skof = (lane & 3) * 8;       // 0,8,16,24

    for (int k0 = 0; k0 < K; k0 += 32) {
        #pragma unroll
        for (int i = 0; i < 2; ++i) {
            const int c = wave * 2 + i;                 // chunk 0..7, uniform in wave
            const int row = c * 16 + srow;
            const bfbits* ga = A + (size_t)(m0 + row) * K + k0 + skof;
            const bfbits* gb = Bt + (size_t)(n0 + row) * K + k0 + skof;
            __builtin_amdgcn_global_load_lds(
                (const __attribute__((address_space(1))) void*)ga,
                (__attribute__((address_space(3))) void*)(As + c * 512), 16, 0, 0);
            __builtin_amdgcn_global_load_lds(
                (const __attribute__((address_space(1))) void*)gb,
                (__attribute__((address_space(3))) void*)(Bs + c * 512), 16, 0, 0);
        }
        __syncthreads();

        short8 af[4], bfv[4];
        #pragma unroll
        for (int i = 0; i < 4; ++i) {
            af[i]  = *(const short8*)(As + (wm + i * 16 + lr) * 32 + quad * 8);
            bfv[i] = *(const short8*)(Bs + (wn + i * 16 + lr) * 32 + quad * 8);
        }
        #pragma unroll
        for (int i = 0; i < 4; ++i)
            #pragma unroll
            for (int j = 0; j < 4; ++j)
                acc[i][j] = __builtin_amdgcn_mfma_f32_16x16x32_bf16(
                    af[i], bfv[j], acc[i][j], 0, 0, 0);
        __syncthreads();
    }

    #pragma unroll
    for (int i = 0; i < 4; ++i) {
        #pragma unroll
        for (int j = 0; j < 4; ++j) {
            const int gc = n0 + wn + j * 16 + lr;
            const float bv = bias[gc];
            #pragma unroll
            for (int r = 0; r < 4; ++r) {
                const int gm = m0 + wm + i * 16 + quad * 4 + r;
                float v = acc[i][j][r] + bv;
                if (RES) v += res[(size_t)gm * N + gc];
                if (WF32) Cf[(size_t)gm * N + gc] = v;
                if (GELU) Cb[(size_t)gm * N + gc] = f2bf(gelu_exact(v));
                else if (WBF) Cb[(size_t)gm * N + gc] = f2bf(v);
            }
        }
    }
}

// ---------------------------------------------------------------------------
// Row LayerNorm over D=512; writes fp32 + bf16 copies.
// ---------------------------------------------------------------------------
__global__ __launch_bounds__(256) void ln2_kernel(
    const float* __restrict__ h, const float* __restrict__ g,
    const float* __restrict__ be, float* __restrict__ outf,
    bfbits* __restrict__ outb)
{
    __shared__ float red[256];
    const int row = blockIdx.x;
    const int tid = threadIdx.x;
    float v0 = h[(size_t)row * D_ + tid];
    float v1 = h[(size_t)row * D_ + 256 + tid];
    red[tid] = v0 + v1;
    __syncthreads();
    for (int s = 128; s > 0; s >>= 1) {
        if (tid < s) red[tid] += red[tid + s];
        __syncthreads();
    }
    float mu = red[0] * (1.0f / 512.0f);
    __syncthreads();
    float d0 = v0 - mu, d1 = v1 - mu;
    red[tid] = d0 * d0 + d1 * d1;
    __syncthreads();
    for (int s = 128; s > 0; s >>= 1) {
        if (tid < s) red[tid] += red[tid + s];
        __syncthreads();
    }
    float var = red[0] * (1.0f / 512.0f);
    float sc = rsqrtf(var + 1e-5f);
    float o0 = g[tid] * d0 * sc + be[tid];
    float o1 = g[256 + tid] * d1 * sc + be[256 + tid];
    outf[(size_t)row * D_ + tid]       = o0;
    outf[(size_t)row * D_ + 256 + tid] = o1;
    outb[(size_t)row * D_ + tid]       = f2bf(o0);
    outb[(size_t)row * D_ + 256 + tid] = f2bf(o1);
}

// ---------------------------------------------------------------------------
// Fused attention, one block per (b,h). bf16 q/k/v; fp32 math; writes bf16 o
// and per-head probabilities to aprob[b][h][q][k] (reduced to aw separately).
// LDS = 12.5KB (q head, bf16) + 9.8KB (scores) -> 7 blocks/CU.
// ---------------------------------------------------------------------------
__global__ __launch_bounds__(256) void attn_kernel(
    const bfbits* __restrict__ q, const bfbits* __restrict__ k,
    const bfbits* __restrict__ v, bfbits* __restrict__ o,
    float* __restrict__ aprob)
{
    __shared__ bfbits qs[SQ_ * DH_];    // 49*128 bf16 = 12544 B
    __shared__ float sc[SQ_ * SK_];     // 9800 B
    const int bh = blockIdx.x;
    const int b = bh >> 2, h = bh & (H_ - 1);
    const int tid = threadIdx.x;

    // stage this head's q rows into LDS (bf16)
    for (int e = tid; e < SQ_ * 32; e += 256) {
        int s = e >> 5, dv = e & 31;
        *(ushort4*)(qs + s * DH_ + dv * 4) =
            *(const ushort4*)(q + ((size_t)(b * SQ_ + s)) * D_ + h * DH_ + dv * 4);
    }
    __syncthreads();

    // scores: 2450 dot products of length 128
    for (int e = tid; e < SQ_ * SK_; e += 256) {
        int qi = e / SK_, ki = e - qi * SK_;
        const ushort4* ka = (const ushort4*)(k + ((size_t)(b * SK_ + ki)) * D_ + h * DH_);
        const ushort4* qa = (const ushort4*)(qs + qi * DH_);
        float sum = 0.f;
        #pragma unroll
        for (int t = 0; t < 32; ++t) {
            ushort4 ku = ka[t], qu = qa[t];
            sum += bf2f(qu.x) * bf2f(ku.x) + bf2f(qu.y) * bf2f(ku.y)
                 + bf2f(qu.z) * bf2f(ku.z) + bf2f(qu.w) * bf2f(ku.w);
        }
        sc[e] = sum * 0.08838834764831845f;  // 1/sqrt(128)
    }
    __syncthreads();

    // softmax: 4 lanes per row (49 rows -> 196 threads), shfl_xor reduce
    if (tid < SQ_ * 4) {
        const int row = tid >> 2, l = tid & 3;
        float* sr = sc + row * SK_;
        float mx = -1e30f;
        for (int ki = l; ki < SK_; ki += 4) mx = fmaxf(mx, sr[ki]);
        mx = fmaxf(mx, __shfl_xor(mx, 1));
        mx = fmaxf(mx, __shfl_xor(mx, 2));
        float sum = 0.f;
        for (int ki = l; ki < SK_; ki += 4) {
            float ev = expf(sr[ki] - mx);
            sr[ki] = ev;
            sum += ev;
        }
        sum += __shfl_xor(sum, 1);
        sum += __shfl_xor(sum, 2);
        float inv = 1.0f / sum;
        for (int ki = l; ki < SK_; ki += 4) sr[ki] *= inv;
    }
    __syncthreads();

    // store probabilities for the aw reduction (coalesced, 2450 floats)
    for (int e = tid; e < SQ_ * SK_; e += 256)
        aprob[(size_t)bh * (SQ_ * SK_) + e] = sc[e];

    // PV: o[qi, dv*4 .. dv*4+3]
    for (int e = tid; e < SQ_ * 32; e += 256) {
        int qi = e >> 5, dv = e & 31;
        const bfbits* vg = v + ((size_t)(b * SK_)) * D_ + h * DH_ + dv * 4;
        const float* sr = sc + qi * SK_;
        float4 sum = {0.f, 0.f, 0.f, 0.f};
        for (int ki = 0; ki < SK_; ++ki) {
            float a = sr[ki];
            ushort4 u = *(const ushort4*)(vg + (size_t)ki * D_);
            sum.x = fmaf(a, bf2f(u.x), sum.x);
            sum.y = fmaf(a, bf2f(u.y), sum.y);
            sum.z = fmaf(a, bf2f(u.z), sum.z);
            sum.w = fmaf(a, bf2f(u.w), sum.w);
        }
        ushort4 ou;
        ou.x = f2bf(sum.x); ou.y = f2bf(sum.y);
        ou.z = f2bf(sum.z); ou.w = f2bf(sum.w);
        *(ushort4*)(o + ((size_t)(b * SQ_ + qi)) * D_ + h * DH_ + dv * 4) = ou;
    }
}

// ---------------------------------------------------------------------------
// aw[b,q,k] = 0.25 * sum_h aprob[b,h,q,k]
// ---------------------------------------------------------------------------
__global__ __launch_bounds__(256) void aw_reduce(
    const float* __restrict__ aprob, float* __restrict__ aw)
{
    const int i = blockIdx.x * 256 + threadIdx.x;
    if (i >= B_ * SQ_ * SK_) return;
    const int b = i / (SQ_ * SK_);
    const int e = i - b * (SQ_ * SK_);
    const float* p = aprob + ((size_t)b * H_) * (SQ_ * SK_) + e;
    aw[i] = 0.25f * (p[0] + p[SQ_ * SK_] + p[2 * SQ_ * SK_] + p[3 * SQ_ * SK_]);
}

// ---------------------------------------------------------------------------
// avg_attn -> n1; cls -> n2 (fp32)
// ---------------------------------------------------------------------------
__global__ __launch_bounds__(256) void norm_kernel(
    const float* __restrict__ ao, const float* __restrict__ pt,
    float* __restrict__ n1, float* __restrict__ n2)
{
    __shared__ float red[256];
    const int b = blockIdx.x, tid = threadIdx.x;
    float s0 = 0.f, s1 = 0.f;
    for (int s = 0; s < SQ_; ++s) {
        s0 += ao[((size_t)(b * SQ_ + s)) * D_ + tid];
        s1 += ao[((size_t)(b * SQ_ + s)) * D_ + 256 + tid];
    }
    s0 *= (1.0f / 49.0f);
    s1 *= (1.0f / 49.0f);
    red[tid] = s0 * s0 + s1 * s1;
    __syncthreads();
    for (int st = 128; st > 0; st >>= 1) {
        if (tid < st) red[tid] += red[tid + st];
        __syncthreads();
    }
    float inv = rsqrtf(red[0]);
    __syncthreads();
    n1[(size_t)b * D_ + tid] = s0 * inv;
    n1[(size_t)b * D_ + 256 + tid] = s1 * inv;

    float c0 = pt[((size_t)(b * SK_)) * D_ + tid];
    float c1 = pt[((size_t)(b * SK_)) * D_ + 256 + tid];
    red[tid] = c0 * c0 + c1 * c1;
    __syncthreads();
    for (int st = 128; st > 0; st >>= 1) {
        if (tid < st) red[tid] += red[tid + st];
        __syncthreads();
    }
    float inv2 = rsqrtf(red[0]);
    n2[(size_t)b * D_ + tid] = c0 * inv2;
    n2[(size_t)b * D_ + 256 + tid] = c1 * inv2;
}

// ---------------------------------------------------------------------------
// fp32 score GEMM: C[512,512] = n1[512,512] @ n2[512,512]^T  (tiny)
// ---------------------------------------------------------------------------
__global__ __launch_bounds__(256) void score_gemm(
    const float* __restrict__ A, const float* __restrict__ Bm,
    float* __restrict__ C)
{
    const int BM = 64, BN = 64, BK = 16, Kt = 512, Nt = 512;
    __shared__ float As[BK][BM + 1];
    __shared__ float Bs[BK][BN + 1];
    const int tid = threadIdx.x;
    const int m0 = blockIdx.y * BM, n0 = blockIdx.x * BN;
    const int tc = tid & 15, tr = tid >> 4;
    float acc[4][4] = {};
    for (int k0 = 0; k0 < Kt; k0 += BK) {
        #pragma unroll
        for (int i = 0; i < 4; ++i) {
            int idx = tid + i * 256;
            int m = idx >> 4, kk = idx & 15;
            As[kk][m] = A[(size_t)(m0 + m) * Kt + k0 + kk];
            Bs[kk][m] = Bm[(size_t)(n0 + m) * Kt + k0 + kk];
        }
        __syncthreads();
        #pragma unroll
        for (int kk = 0; kk < BK; ++kk) {
            float a4[4], b4[4];
            #pragma unroll
            for (int i = 0; i < 4; ++i) a4[i] = As[kk][tr * 4 + i];
            #pragma unroll
            for (int j = 0; j < 4; ++j) b4[j] = Bs[kk][tc * 4 + j];
            #pragma unroll
            for (int i = 0; i < 4; ++i)
                #pragma unroll
                for (int j = 0; j < 4; ++j)
                    acc[i][j] = fmaf(a4[i], b4[j], acc[i][j]);
        }
        __syncthreads();
    }
    #pragma unroll
    for (int i = 0; i < 4; ++i)
        #pragma unroll
        for (int j = 0; j < 4; ++j)
            C[(size_t)(m0 + tr * 4 + i) * Nt + n0 + tc * 4 + j] = acc[i][j];
}

extern "C" void kernel_launch(void* const* d_in, const int* in_sizes, int n_in,
                              void* d_out, int out_size, void* d_ws, size_t ws_size,
                              hipStream_t stream)
{
    const float* img = (const float*)d_in[0];
    const float* txt = (const float*)d_in[1];
    const float* Wi1 = (const float*)d_in[2];  const float* bi1 = (const float*)d_in[3];
    const float* Wi2 = (const float*)d_in[4];  const float* bi2 = (const float*)d_in[5];
    const float* gi  = (const float*)d_in[6];  const float* bei = (const float*)d_in[7];
    const float* Wt1 = (const float*)d_in[8];  const float* bt1 = (const float*)d_in[9];
    const float* Wt2 = (const float*)d_in[10]; const float* bt2 = (const float*)d_in[11];
    const float* gt  = (const float*)d_in[12]; const float* bet = (const float*)d_in[13];
    const float* Wq  = (const float*)d_in[14]; const float* bq  = (const float*)d_in[15];
    const float* Wk  = (const float*)d_in[16]; const float* bk  = (const float*)d_in[17];
    const float* Wv  = (const float*)d_in[18]; const float* bv  = (const float*)d_in[19];
    const float* Wo  = (const float*)d_in[20]; const float* bo  = (const float*)d_in[21];
    float* out = (float*)d_out;

    // ---- workspace layout (~230 MiB) ----
    bfbits* Wi1T = (bfbits*)d_ws;                 // 2048*512
    bfbits* Wi2T = Wi1T + 1048576;                // 512*512
    bfbits* Wt1T = Wi2T + 262144;                 // 768*512
    bfbits* Wt2T = Wt1T + 393216;
    bfbits* WqT  = Wt2T + 262144;
    bfbits* WkT  = WqT  + 262144;
    bfbits* WvT  = WkT  + 262144;
    bfbits* WoT  = WvT  + 262144;
    bfbits* R1   = WoT  + 262144;                 // 51,380,224 bf16 elems
    bfbits* Aimg = R1;                            // 25088*2048
    bfbits* Atxt = R1;                            // 25600*768 (after img phase)
    float*  aprob = (float*)R1;                   // 512*4*49*50 floats (attn phase;
                                                  //  Aimg/Atxt dead by then, < 40MB region)
    bfbits* Qbf  = R1 + 20000000;                 // 25088*512
    bfbits* Kbf  = R1 + 33200000;                 // 25600*512
    float*  R2   = (float*)(R1 + 51380224);       // 13,107,200 floats (P/H)
    bfbits* Vbf  = (bfbits*)R2;                   // 25600*512 (after H dead)
    bfbits* R3   = (bfbits*)(R2 + 13107200);      // 13,107,200 bf16 (G / Obf)
    bfbits* Obf  = R3;
    bfbits* PiBf = R3 + 13107200;                 // 25088*512
    bfbits* PtBf = PiBf + 12845056;               // 25600*512
    float*  n1   = (float*)(PtBf + 13107200);
    float*  n2   = n1 + 262144;

    const int MI = B_ * SQ_;   // 25088
    const int MT = B_ * SK_;   // 25600
    dim3 blk(256);

    // weights -> transposed bf16
    wcast_t<<<dim3(DIMG_ / 32, D_ / 32), blk, 0, stream>>>(Wi1, Wi1T, DIMG_, D_);
    wcast_t<<<dim3(D_ / 32, D_ / 32),    blk, 0, stream>>>(Wi2, Wi2T, D_, D_);
    wcast_t<<<dim3(DTXT_ / 32, D_ / 32), blk, 0, stream>>>(Wt1, Wt1T, DTXT_, D_);
    wcast_t<<<dim3(D_ / 32, D_ / 32),    blk, 0, stream>>>(Wt2, Wt2T, D_, D_);
    wcast_t<<<dim3(D_ / 32, D_ / 32),    blk, 0, stream>>>(Wq, WqT, D_, D_);
    wcast_t<<<dim3(D_ / 32, D_ / 32),    blk, 0, stream>>>(Wk, WkT, D_, D_);
    wcast_t<<<dim3(D_ / 32, D_ / 32),    blk, 0, stream>>>(Wv, WvT, D_, D_);
    wcast_t<<<dim3(D_ / 32, D_ / 32),    blk, 0, stream>>>(Wo, WoT, D_, D_);

    // ---- image head ----
    img_t<<<dim3(DIMG_ / 64, B_), blk, 0, stream>>>(img, Aimg);
    gemm_bf16<false, true, true, true><<<dim3(4, MI / 128), blk, 0, stream>>>(
        Aimg, Wi1T, bi1, nullptr, R2, R3, MI, DIMG_);            // p fp32 + gelu bf16
    gemm_bf16<true, false, true, false><<<dim3(4, MI / 128), blk, 0, stream>>>(
        R3, Wi2T, bi2, R2, R2, nullptr, MI, D_);                 // h = g@W2+b2+p (in-place)
    ln2_kernel<<<dim3(MI), blk, 0, stream>>>(R2, gi, bei, out + PI_OFF, PiBf);

    // ---- text head ----
    cast4<<<dim3((MT * DTXT_ / 4 + 255) / 256), blk, 0, stream>>>(txt, Atxt, MT * DTXT_ / 4);
    gemm_bf16<false, true, true, true><<<dim3(4, MT / 128), blk, 0, stream>>>(
        Atxt, Wt1T, bt1, nullptr, R2, R3, MT, DTXT_);
    gemm_bf16<true, false, true, false><<<dim3(4, MT / 128), blk, 0, stream>>>(
        R3, Wt2T, bt2, R2, R2, nullptr, MT, D_);
    ln2_kernel<<<dim3(MT), blk, 0, stream>>>(R2, gt, bet, out + PT_OFF, PtBf);

    // ---- q, k, v (bf16 out) ----
    gemm_bf16<false, false, false, true><<<dim3(4, MI / 128), blk, 0, stream>>>(
        PiBf, WqT, bq, nullptr, nullptr, Qbf, MI, D_);
    gemm_bf16<false, false, false, true><<<dim3(4, MT / 128), blk, 0, stream>>>(
        PtBf, WkT, bk, nullptr, nullptr, Kbf, MT, D_);
    gemm_bf16<false, false, false, true><<<dim3(4, MT / 128), blk, 0, stream>>>(
        PtBf, WvT, bv, nullptr, nullptr, Vbf, MT, D_);

    // ---- attention: one block per (b,h) ----
    attn_kernel<<<dim3(B_ * H_), blk, 0, stream>>>(Qbf, Kbf, Vbf, Obf, aprob);
    aw_reduce<<<dim3((B_ * SQ_ * SK_ + 255) / 256), blk, 0, stream>>>(aprob, out + AW_OFF);

    // ---- output projection ----
    gemm_bf16<false, false, true, false><<<dim3(4, MI / 128), blk, 0, stream>>>(
        Obf, WoT, bo, nullptr, out + AO_OFF, nullptr, MI, D_);

    // ---- similarity score ----
    norm_kernel<<<dim3(B_), blk, 0, stream>>>(out + AO_OFF, out + PT_OFF, n1, n2);
    score_gemm<<<dim3(8, 8), blk, 0, stream>>>(n1, n2, out + SCORE_OFF);
}

// Round 2
// 1092.225 us; speedup vs baseline: 1.1676x; 1.1676x over previous
//
#include <hip/hip_runtime.h>
#include <math.h>

#define B_    512
#define SQ_   49
#define SK_   50
#define DIMG_ 2048
#define DTXT_ 768
#define D_    512
#define H_    4
#define DH_   128

// output offsets (floats): score, attn_output, attn_weights, pi, pt
#define SCORE_OFF 0
#define AO_OFF    262144      // 512*512
#define AW_OFF    13107200    // + 512*49*512
#define PI_OFF    14361600    // + 512*49*50
#define PT_OFF    27206656    // + 512*49*512

typedef unsigned short bfbits;
typedef __attribute__((ext_vector_type(8))) short short8;
typedef __attribute__((ext_vector_type(4))) float floatx4;

static __device__ __forceinline__ bfbits f2bf(float f) {
    union { float f; unsigned u; } a; a.f = f;
    return (bfbits)((a.u + 0x7fffu + ((a.u >> 16) & 1u)) >> 16);
}
static __device__ __forceinline__ float bf2f(bfbits b) {
    union { unsigned u; float f; } a; a.u = ((unsigned)b) << 16;
    return a.f;
}
static __device__ __forceinline__ float gelu_exact(float x) {
    return 0.5f * x * (1.0f + erff(x * 0.70710678118654752f));
}

// ---------------------------------------------------------------------------
// Weight transpose+cast: W (K,N) fp32 -> Wt (N,K) bf16.  K,N % 32 == 0.
// ---------------------------------------------------------------------------
__global__ __launch_bounds__(256) void wcast_t(
    const float* __restrict__ W, bfbits* __restrict__ Wt, int K, int N)
{
    __shared__ float t[32][33];
    const int k0 = blockIdx.x * 32, n0 = blockIdx.y * 32;
    const int tx = threadIdx.x & 31, ty = threadIdx.x >> 5;  // 32 x 8
    #pragma unroll
    for (int i = 0; i < 32; i += 8)
        t[ty + i][tx] = W[(size_t)(k0 + ty + i) * N + n0 + tx];
    __syncthreads();
    #pragma unroll
    for (int i = 0; i < 32; i += 8)
        Wt[(size_t)(n0 + ty + i) * K + k0 + tx] = f2bf(t[tx][ty + i]);
}

// ---------------------------------------------------------------------------
// Image transpose+cast: img[b, k, s] fp32 -> A[(b*49+s), k] bf16 (K=2048)
// block = (k-tile of 64, b)
// ---------------------------------------------------------------------------
__global__ __launch_bounds__(256) void img_t(
    const float* __restrict__ img, bfbits* __restrict__ A)
{
    __shared__ float t[64][50];
    const int b = blockIdx.y, k0 = blockIdx.x * 64;
    const float* src = img + (size_t)b * (DIMG_ * SQ_) + (size_t)k0 * SQ_;
    for (int e = threadIdx.x; e < 64 * 49; e += 256) {
        int kl = e / 49, s = e - kl * 49;
        t[kl][s] = src[kl * 49 + s];
    }
    __syncthreads();
    bfbits* dst = A + (size_t)b * SQ_ * DIMG_ + k0;
    for (int e = threadIdx.x; e < 49 * 64; e += 256) {
        int s = e >> 6, kl = e & 63;
        dst[(size_t)s * DIMG_ + kl] = f2bf(t[kl][s]);
    }
}

// ---------------------------------------------------------------------------
// Flat fp32 -> bf16 cast, 4 elements/thread. n % 4 == 0.
// ---------------------------------------------------------------------------
__global__ __launch_bounds__(256) void cast4(
    const float* __restrict__ x, bfbits* __restrict__ y, int n4)
{
    int i = blockIdx.x * 256 + threadIdx.x;
    if (i < n4) {
        float4 v = ((const float4*)x)[i];
        ushort4 u;
        u.x = f2bf(v.x); u.y = f2bf(v.y); u.z = f2bf(v.z); u.w = f2bf(v.w);
        ((ushort4*)y)[i] = u;
    }
}

// ---------------------------------------------------------------------------
// bf16 MFMA GEMM: C[M,512] = A[M,K] @ Bt[512,K]^T + bias (+res fp32).
// 128x128 tile, BK=32, 4 waves (64x64 each, 4x4 MFMA grid), global_load_lds.
// M%128==0, K%32==0. res may alias Cf (element-wise read-then-write).
// GELU: Cb=gelu(v) bf16, Cf=v fp32. Else WBF: Cb=bf16(v). WF32: Cf=v.
// ---------------------------------------------------------------------------
template<bool RES, bool GELU, bool WF32, bool WBF>
__global__ __launch_bounds__(256) void gemm_bf16(
    const bfbits* __restrict__ A, const bfbits* __restrict__ Bt,
    const float* __restrict__ bias, const float* res,
    float* Cf, bfbits* __restrict__ Cb, int M, int K)
{
    constexpr int N = 512;
    __shared__ __attribute__((aligned(16))) bfbits As[128 * 32];
    __shared__ __attribute__((aligned(16))) bfbits Bs[128 * 32];
    const int tid  = threadIdx.x;
    const int wave = tid >> 6, lane = tid & 63;
    const int m0 = blockIdx.y * 128, n0 = blockIdx.x * 128;
    const int wm = (wave >> 1) * 64, wn = (wave & 1) * 64;
    const int lr = lane & 15, quad = lane >> 4;

    floatx4 acc[4][4];
    #pragma unroll
    for (int i = 0; i < 4; ++i)
        #pragma unroll
        for (int j = 0; j < 4; ++j) acc[i][j] = 0.0f;

    // per-lane source row/col offset for staging (chunk c: rows c*16+(lane>>2))
    const int srow = lane >> 2;            // 0..15
    const int skof = (lane & 3) * 8;       // 0,8,16,24

    for (int k0 = 0; k0 < K; k0 += 32) {
        #pragma unroll
        for (int i = 0; i < 2; ++i) {
            const int c = wave * 2 + i;                 // chunk 0..7, uniform in wave
            const int row = c * 16 + srow;
            const bfbits* ga = A + (size_t)(m0 + row) * K + k0 + skof;
            const bfbits* gb = Bt + (size_t)(n0 + row) * K + k0 + skof;
            __builtin_amdgcn_global_load_lds(
                (const __attribute__((address_space(1))) void*)ga,
                (__attribute__((address_space(3))) void*)(As + c * 512), 16, 0, 0);
            __builtin_amdgcn_global_load_lds(
                (const __attribute__((address_space(1))) void*)gb,
                (__attribute__((address_space(3))) void*)(Bs + c * 512), 16, 0, 0);
        }
        __syncthreads();

        short8 af[4], bfv[4];
        #pragma unroll
        for (int i = 0; i < 4; ++i) {
            af[i]  = *(const short8*)(As + (wm + i * 16 + lr) * 32 + quad * 8);
            bfv[i] = *(const short8*)(Bs + (wn + i * 16 + lr) * 32 + quad * 8);
        }
        #pragma unroll
        for (int i = 0; i < 4; ++i)
            #pragma unroll
            for (int j = 0; j < 4; ++j)
                acc[i][j] = __builtin_amdgcn_mfma_f32_16x16x32_bf16(
                    af[i], bfv[j], acc[i][j], 0, 0, 0);
        __syncthreads();
    }

    #pragma unroll
    for (int i = 0; i < 4; ++i) {
        #pragma unroll
        for (int j = 0; j < 4; ++j) {
            const int gc = n0 + wn + j * 16 + lr;
            const float bv = bias[gc];
            #pragma unroll
            for (int r = 0; r < 4; ++r) {
                const int gm = m0 + wm + i * 16 + quad * 4 + r;
                float v = acc[i][j][r] + bv;
                if (RES) v += res[(size_t)gm * N + gc];
                if (WF32) Cf[(size_t)gm * N + gc] = v;
                if (GELU) Cb[(size_t)gm * N + gc] = f2bf(gelu_exact(v));
                else if (WBF) Cb[(size_t)gm * N + gc] = f2bf(v);
            }
        }
    }
}

// ---------------------------------------------------------------------------
// Row LayerNorm over D=512; writes fp32 + bf16 copies.
// ---------------------------------------------------------------------------
__global__ __launch_bounds__(256) void ln2_kernel(
    const float* __restrict__ h, const float* __restrict__ g,
    const float* __restrict__ be, float* __restrict__ outf,
    bfbits* __restrict__ outb)
{
    __shared__ float red[256];
    const int row = blockIdx.x;
    const int tid = threadIdx.x;
    float v0 = h[(size_t)row * D_ + tid];
    float v1 = h[(size_t)row * D_ + 256 + tid];
    red[tid] = v0 + v1;
    __syncthreads();
    for (int s = 128; s > 0; s >>= 1) {
        if (tid < s) red[tid] += red[tid + s];
        __syncthreads();
    }
    float mu = red[0] * (1.0f / 512.0f);
    __syncthreads();
    float d0 = v0 - mu, d1 = v1 - mu;
    red[tid] = d0 * d0 + d1 * d1;
    __syncthreads();
    for (int s = 128; s > 0; s >>= 1) {
        if (tid < s) red[tid] += red[tid + s];
        __syncthreads();
    }
    float var = red[0] * (1.0f / 512.0f);
    float sc = rsqrtf(var + 1e-5f);
    float o0 = g[tid] * d0 * sc + be[tid];
    float o1 = g[256 + tid] * d1 * sc + be[256 + tid];
    outf[(size_t)row * D_ + tid]       = o0;
    outf[(size_t)row * D_ + 256 + tid] = o1;
    outb[(size_t)row * D_ + tid]       = f2bf(o0);
    outb[(size_t)row * D_ + 256 + tid] = f2bf(o1);
}

// ---------------------------------------------------------------------------
// Fused attention: one block per batch b, one wave per head.
// QK^T via MFMA computing S^T[ki][qi] = sum_d K[ki][d]*Q[qi][d]  (both row
// reads). Softmax over ki is lane-local(16 vals)+shfl_xor(16,32). P (fp32)
// goes to LDS; aw computed in-block; PV stays scalar (V reads coalesced).
// Padded tiles (49->64, 50->64) read workspace slack, masked to -inf / cut.
// ---------------------------------------------------------------------------
__global__ __launch_bounds__(256) void attn_kernel(
    const bfbits* __restrict__ q, const bfbits* __restrict__ k,
    const bfbits* __restrict__ v, bfbits* __restrict__ o,
    float* __restrict__ aw)
{
    constexpr int ROWF = 69;               // fp32 row stride (banks: 5*qi%32)
    __shared__ float sc[H_][SQ_ * ROWF];   // 54,096 B total
    const int b = blockIdx.x;
    const int tid = threadIdx.x;
    const int h = tid >> 6, lane = tid & 63;
    const int lr = lane & 15, g = lane >> 4;

    const bfbits* kb = k + ((size_t)b * SK_) * D_ + h * DH_;
    const bfbits* qb = q + ((size_t)b * SQ_) * D_ + h * DH_;

    // ---- S^T = K @ Q^T  (64x64 padded, 16 tiles, K-dim 128 = 4 steps) ----
    floatx4 acc[4][4];
    #pragma unroll
    for (int mi = 0; mi < 4; ++mi)
        #pragma unroll
        for (int ni = 0; ni < 4; ++ni) acc[mi][ni] = 0.0f;

    #pragma unroll
    for (int ks = 0; ks < 4; ++ks) {
        short8 afr[4], bfr[4];
        #pragma unroll
        for (int mi = 0; mi < 4; ++mi)
            afr[mi] = *(const short8*)(kb + (size_t)(mi * 16 + lr) * D_ + ks * 32 + g * 8);
        #pragma unroll
        for (int ni = 0; ni < 4; ++ni)
            bfr[ni] = *(const short8*)(qb + (size_t)(ni * 16 + lr) * D_ + ks * 32 + g * 8);
        #pragma unroll
        for (int mi = 0; mi < 4; ++mi)
            #pragma unroll
            for (int ni = 0; ni < 4; ++ni)
                acc[mi][ni] = __builtin_amdgcn_mfma_f32_16x16x32_bf16(
                    afr[mi], bfr[ni], acc[mi][ni], 0, 0, 0);
    }

    // ---- softmax over ki (rows of S^T) per qi column; write P to LDS ----
    const float scale = 0.08838834764831845f;   // 1/sqrt(128)
    #pragma unroll
    for (int ni = 0; ni < 4; ++ni) {
        const int qi = ni * 16 + lr;
        float mx = -1e30f;
        #pragma unroll
        for (int mi = 0; mi < 4; ++mi)
            #pragma unroll
            for (int r = 0; r < 4; ++r) {
                const int ki = mi * 16 + g * 4 + r;
                float s = (ki < SK_) ? acc[mi][ni][r] * scale : -1e30f;
                acc[mi][ni][r] = s;
                mx = fmaxf(mx, s);
            }
        mx = fmaxf(mx, __shfl_xor(mx, 16));
        mx = fmaxf(mx, __shfl_xor(mx, 32));
        float sum = 0.f;
        #pragma unroll
        for (int mi = 0; mi < 4; ++mi)
            #pragma unroll
            for (int r = 0; r < 4; ++r) {
                float ev = __expf(acc[mi][ni][r] - mx);  // masked -> exp(-inf)=0
                acc[mi][ni][r] = ev;
                sum += ev;
            }
        sum += __shfl_xor(sum, 16);
        sum += __shfl_xor(sum, 32);
        const float inv = 1.0f / sum;
        if (qi < SQ_) {
            #pragma unroll
            for (int mi = 0; mi < 4; ++mi) {
                float4 w;
                w.x = acc[mi][ni][0] * inv;
                w.y = acc[mi][ni][1] * inv;
                w.z = acc[mi][ni][2] * inv;
                w.w = acc[mi][ni][3] * inv;
                *(float4*)&sc[h][qi * ROWF + mi * 16 + g * 4] = w;
            }
        }
    }
    __syncthreads();

    // ---- aw[b,qi,ki] = 0.25 * sum_h P ----
    for (int e = tid; e < SQ_ * SK_; e += 256) {
        int qi = e / SK_, ki = e - qi * SK_;
        const int off = qi * ROWF + ki;
        aw[(size_t)b * (SQ_ * SK_) + e] =
            0.25f * (sc[0][off] + sc[1][off] + sc[2][off] + sc[3][off]);
    }

    // ---- PV: scalar fp32, V reads coalesced (L1/L2 resident) ----
    const bfbits* vb = v + ((size_t)b * SK_) * D_ + h * DH_;
    bfbits* ob = o + ((size_t)b * SQ_) * D_ + h * DH_;
    for (int e = lane; e < SQ_ * 16; e += 64) {
        const int qi = e >> 4, dc = e & 15;      // 8 d-elems per chunk
        const float* sr = &sc[h][qi * ROWF];
        float s[8] = {0.f, 0.f, 0.f, 0.f, 0.f, 0.f, 0.f, 0.f};
        for (int ki = 0; ki < SK_; ++ki) {
            const float a = sr[ki];
            short8 u = *(const short8*)(vb + (size_t)ki * D_ + dc * 8);
            #pragma unroll
            for (int j = 0; j < 8; ++j)
                s[j] = fmaf(a, bf2f((bfbits)u[j]), s[j]);
        }
        short8 ov;
        #pragma unroll
        for (int j = 0; j < 8; ++j) ov[j] = (short)f2bf(s[j]);
        *(short8*)(ob + (size_t)qi * D_ + dc * 8) = ov;
    }
}

// ---------------------------------------------------------------------------
// avg_attn -> n1; cls -> n2 (fp32)
// ---------------------------------------------------------------------------
__global__ __launch_bounds__(256) void norm_kernel(
    const float* __restrict__ ao, const float* __restrict__ pt,
    float* __restrict__ n1, float* __restrict__ n2)
{
    __shared__ float red[256];
    const int b = blockIdx.x, tid = threadIdx.x;
    float s0 = 0.f, s1 = 0.f;
    for (int s = 0; s < SQ_; ++s) {
        s0 += ao[((size_t)(b * SQ_ + s)) * D_ + tid];
        s1 += ao[((size_t)(b * SQ_ + s)) * D_ + 256 + tid];
    }
    s0 *= (1.0f / 49.0f);
    s1 *= (1.0f / 49.0f);
    red[tid] = s0 * s0 + s1 * s1;
    __syncthreads();
    for (int st = 128; st > 0; st >>= 1) {
        if (tid < st) red[tid] += red[tid + st];
        __syncthreads();
    }
    float inv = rsqrtf(red[0]);
    __syncthreads();
    n1[(size_t)b * D_ + tid] = s0 * inv;
    n1[(size_t)b * D_ + 256 + tid] = s1 * inv;

    float c0 = pt[((size_t)(b * SK_)) * D_ + tid];
    float c1 = pt[((size_t)(b * SK_)) * D_ + 256 + tid];
    red[tid] = c0 * c0 + c1 * c1;
    __syncthreads();
    for (int st = 128; st > 0; st >>= 1) {
        if (tid < st) red[tid] += red[tid + st];
        __syncthreads();
    }
    float inv2 = rsqrtf(red[0]);
    n2[(size_t)b * D_ + tid] = c0 * inv2;
    n2[(size_t)b * D_ + 256 + tid] = c1 * inv2;
}

// ---------------------------------------------------------------------------
// fp32 score GEMM: C[512,512] = n1[512,512] @ n2[512,512]^T  (tiny)
// ---------------------------------------------------------------------------
__global__ __launch_bounds__(256) void score_gemm(
    const float* __restrict__ A, const float* __restrict__ Bm,
    float* __restrict__ C)
{
    const int BM = 64, BN = 64, BK = 16, Kt = 512, Nt = 512;
    __shared__ float As[BK][BM + 1];
    __shared__ float Bs[BK][BN + 1];
    const int tid = threadIdx.x;
    const int m0 = blockIdx.y * BM, n0 = blockIdx.x * BN;
    const int tc = tid & 15, tr = tid >> 4;
    float acc[4][4] = {};
    for (int k0 = 0; k0 < Kt; k0 += BK) {
        #pragma unroll
        for (int i = 0; i < 4; ++i) {
            int idx = tid + i * 256;
            int m = idx >> 4, kk = idx & 15;
            As[kk][m] = A[(size_t)(m0 + m) * Kt + k0 + kk];
            Bs[kk][m] = Bm[(size_t)(n0 + m) * Kt + k0 + kk];
        }
        __syncthreads();
        #pragma unroll
        for (int kk = 0; kk < BK; ++kk) {
            float a4[4], b4[4];
            #pragma unroll
            for (int i = 0; i < 4; ++i) a4[i] = As[kk][tr * 4 + i];
            #pragma unroll
            for (int j = 0; j < 4; ++j) b4[j] = Bs[kk][tc * 4 + j];
            #pragma unroll
            for (int i = 0; i < 4; ++i)
                #pragma unroll
                for (int j = 0; j < 4; ++j)
                    acc[i][j] = fmaf(a4[i], b4[j], acc[i][j]);
        }
        __syncthreads();
    }
    #pragma unroll
    for (int i = 0; i < 4; ++i)
        #pragma unroll
        for (int j = 0; j < 4; ++j)
            C[(size_t)(m0 + tr * 4 + i) * Nt + n0 + tc * 4 + j] = acc[i][j];
}

extern "C" void kernel_launch(void* const* d_in, const int* in_sizes, int n_in,
                              void* d_out, int out_size, void* d_ws, size_t ws_size,
                              hipStream_t stream)
{
    const float* img = (const float*)d_in[0];
    const float* txt = (const float*)d_in[1];
    const float* Wi1 = (const float*)d_in[2];  const float* bi1 = (const float*)d_in[3];
    const float* Wi2 = (const float*)d_in[4];  const float* bi2 = (const float*)d_in[5];
    const float* gi  = (const float*)d_in[6];  const float* bei = (const float*)d_in[7];
    const float* Wt1 = (const float*)d_in[8];  const float* bt1 = (const float*)d_in[9];
    const float* Wt2 = (const float*)d_in[10]; const float* bt2 = (const float*)d_in[11];
    const float* gt  = (const float*)d_in[12]; const float* bet = (const float*)d_in[13];
    const float* Wq  = (const float*)d_in[14]; const float* bq  = (const float*)d_in[15];
    const float* Wk  = (const float*)d_in[16]; const float* bk  = (const float*)d_in[17];
    const float* Wv  = (const float*)d_in[18]; const float* bv  = (const float*)d_in[19];
    const float* Wo  = (const float*)d_in[20]; const float* bo  = (const float*)d_in[21];
    float* out = (float*)d_out;

    // ---- workspace layout (~230 MiB) ----
    bfbits* Wi1T = (bfbits*)d_ws;                 // 2048*512
    bfbits* Wi2T = Wi1T + 1048576;                // 512*512
    bfbits* Wt1T = Wi2T + 262144;                 // 768*512
    bfbits* Wt2T = Wt1T + 393216;
    bfbits* WqT  = Wt2T + 262144;
    bfbits* WkT  = WqT  + 262144;
    bfbits* WvT  = WkT  + 262144;
    bfbits* WoT  = WvT  + 262144;
    bfbits* R1   = WoT  + 262144;                 // 51,380,224 bf16 elems
    bfbits* Aimg = R1;                            // 25088*2048
    bfbits* Atxt = R1;                            // 25600*768 (after img phase)
    bfbits* Qbf  = R1 + 20000000;                 // 25088*512
    bfbits* Kbf  = R1 + 33200000;                 // 25600*512
    float*  R2   = (float*)(R1 + 51380224);       // 13,107,200 floats (P/H)
    bfbits* Vbf  = (bfbits*)R2;                   // 25600*512 (after H dead)
    bfbits* R3   = (bfbits*)(R2 + 13107200);      // 13,107,200 bf16 (G / Obf)
    bfbits* Obf  = R3;
    bfbits* PiBf = R3 + 13107200;                 // 25088*512
    bfbits* PtBf = PiBf + 12845056;               // 25600*512
    float*  n1   = (float*)(PtBf + 13107200);
    float*  n2   = n1 + 262144;

    const int MI = B_ * SQ_;   // 25088
    const int MT = B_ * SK_;   // 25600
    dim3 blk(256);

    // weights -> transposed bf16
    wcast_t<<<dim3(DIMG_ / 32, D_ / 32), blk, 0, stream>>>(Wi1, Wi1T, DIMG_, D_);
    wcast_t<<<dim3(D_ / 32, D_ / 32),    blk, 0, stream>>>(Wi2, Wi2T, D_, D_);
    wcast_t<<<dim3(DTXT_ / 32, D_ / 32), blk, 0, stream>>>(Wt1, Wt1T, DTXT_, D_);
    wcast_t<<<dim3(D_ / 32, D_ / 32),    blk, 0, stream>>>(Wt2, Wt2T, D_, D_);
    wcast_t<<<dim3(D_ / 32, D_ / 32),    blk, 0, stream>>>(Wq, WqT, D_, D_);
    wcast_t<<<dim3(D_ / 32, D_ / 32),    blk, 0, stream>>>(Wk, WkT, D_, D_);
    wcast_t<<<dim3(D_ / 32, D_ / 32),    blk, 0, stream>>>(Wv, WvT, D_, D_);
    wcast_t<<<dim3(D_ / 32, D_ / 32),    blk, 0, stream>>>(Wo, WoT, D_, D_);

    // ---- image head ----
    img_t<<<dim3(DIMG_ / 64, B_), blk, 0, stream>>>(img, Aimg);
    gemm_bf16<false, true, true, true><<<dim3(4, MI / 128), blk, 0, stream>>>(
        Aimg, Wi1T, bi1, nullptr, R2, R3, MI, DIMG_);            // p fp32 + gelu bf16
    gemm_bf16<true, false, true, false><<<dim3(4, MI / 128), blk, 0, stream>>>(
        R3, Wi2T, bi2, R2, R2, nullptr, MI, D_);                 // h = g@W2+b2+p (in-place)
    ln2_kernel<<<dim3(MI), blk, 0, stream>>>(R2, gi, bei, out + PI_OFF, PiBf);

    // ---- text head ----
    cast4<<<dim3((MT * DTXT_ / 4 + 255) / 256), blk, 0, stream>>>(txt, Atxt, MT * DTXT_ / 4);
    gemm_bf16<false, true, true, true><<<dim3(4, MT / 128), blk, 0, stream>>>(
        Atxt, Wt1T, bt1, nullptr, R2, R3, MT, DTXT_);
    gemm_bf16<true, false, true, false><<<dim3(4, MT / 128), blk, 0, stream>>>(
        R3, Wt2T, bt2, R2, R2, nullptr, MT, D_);
    ln2_kernel<<<dim3(MT), blk, 0, stream>>>(R2, gt, bet, out + PT_OFF, PtBf);

    // ---- q, k, v (bf16 out) ----
    gemm_bf16<false, false, false, true><<<dim3(4, MI / 128), blk, 0, stream>>>(
        PiBf, WqT, bq, nullptr, nullptr, Qbf, MI, D_);
    gemm_bf16<false, false, false, true><<<dim3(4, MT / 128), blk, 0, stream>>>(
        PtBf, WkT, bk, nullptr, nullptr, Kbf, MT, D_);
    gemm_bf16<false, false, false, true><<<dim3(4, MT / 128), blk, 0, stream>>>(
        PtBf, WvT, bv, nullptr, nullptr, Vbf, MT, D_);

    // ---- attention: one block per batch, one wave per head ----
    attn_kernel<<<dim3(B_), blk, 0, stream>>>(Qbf, Kbf, Vbf, Obf, out + AW_OFF);

    // ---- output projection ----
    gemm_bf16<false, false, true, false><<<dim3(4, MI / 128), blk, 0, stream>>>(
        Obf, WoT, bo, nullptr, out + AO_OFF, nullptr, MI, D_);

    // ---- similarity score ----
    norm_kernel<<<dim3(B_), blk, 0, stream>>>(out + AO_OFF, out + PT_OFF, n1, n2);
    score_gemm<<<dim3(8, 8), blk, 0, stream>>>(n1, n2, out + SCORE_OFF);
}

// Round 3
// 1048.664 us; speedup vs baseline: 1.2161x; 1.0415x over previous
//
#include <hip/hip_runtime.h>
#include <math.h>

#define B_    512
#define SQ_   49
#define SK_   50
#define DIMG_ 2048
#define DTXT_ 768
#define D_    512
#define H_    4
#define DH_   128

// output offsets (floats): score, attn_output, attn_weights, pi, pt
#define SCORE_OFF 0
#define AO_OFF    262144      // 512*512
#define AW_OFF    13107200    // + 512*49*512
#define PI_OFF    14361600    // + 512*49*50
#define PT_OFF    27206656    // + 512*49*512

typedef unsigned short bfbits;
typedef __attribute__((ext_vector_type(8))) short short8;
typedef __attribute__((ext_vector_type(4))) float floatx4;

static __device__ __forceinline__ bfbits f2bf(float f) {
    union { float f; unsigned u; } a; a.f = f;
    return (bfbits)((a.u + 0x7fffu + ((a.u >> 16) & 1u)) >> 16);
}
static __device__ __forceinline__ float bf2f(bfbits b) {
    union { unsigned u; float f; } a; a.u = ((unsigned)b) << 16;
    return a.f;
}
static __device__ __forceinline__ float gelu_exact(float x) {
    return 0.5f * x * (1.0f + erff(x * 0.70710678118654752f));
}

// ---------------------------------------------------------------------------
// Weight transpose+cast: W (K,N) fp32 -> Wt (N,K) bf16.  K,N % 32 == 0.
// ---------------------------------------------------------------------------
__global__ __launch_bounds__(256) void wcast_t(
    const float* __restrict__ W, bfbits* __restrict__ Wt, int K, int N)
{
    __shared__ float t[32][33];
    const int k0 = blockIdx.x * 32, n0 = blockIdx.y * 32;
    const int tx = threadIdx.x & 31, ty = threadIdx.x >> 5;  // 32 x 8
    #pragma unroll
    for (int i = 0; i < 32; i += 8)
        t[ty + i][tx] = W[(size_t)(k0 + ty + i) * N + n0 + tx];
    __syncthreads();
    #pragma unroll
    for (int i = 0; i < 32; i += 8)
        Wt[(size_t)(n0 + ty + i) * K + k0 + tx] = f2bf(t[tx][ty + i]);
}

// ---------------------------------------------------------------------------
// Image transpose+cast: img[b, k, s] fp32 -> A[(b*49+s), k] bf16 (K=2048)
// block = (k-tile of 64, b)
// ---------------------------------------------------------------------------
__global__ __launch_bounds__(256) void img_t(
    const float* __restrict__ img, bfbits* __restrict__ A)
{
    __shared__ float t[64][50];
    const int b = blockIdx.y, k0 = blockIdx.x * 64;
    const float* src = img + (size_t)b * (DIMG_ * SQ_) + (size_t)k0 * SQ_;
    for (int e = threadIdx.x; e < 64 * 49; e += 256) {
        int kl = e / 49, s = e - kl * 49;
        t[kl][s] = src[kl * 49 + s];
    }
    __syncthreads();
    bfbits* dst = A + (size_t)b * SQ_ * DIMG_ + k0;
    for (int e = threadIdx.x; e < 49 * 64; e += 256) {
        int s = e >> 6, kl = e & 63;
        dst[(size_t)s * DIMG_ + kl] = f2bf(t[kl][s]);
    }
}

// ---------------------------------------------------------------------------
// Flat fp32 -> bf16 cast, 4 elements/thread. n % 4 == 0.
// ---------------------------------------------------------------------------
__global__ __launch_bounds__(256) void cast4(
    const float* __restrict__ x, bfbits* __restrict__ y, int n4)
{
    int i = blockIdx.x * 256 + threadIdx.x;
    if (i < n4) {
        float4 v = ((const float4*)x)[i];
        ushort4 u;
        u.x = f2bf(v.x); u.y = f2bf(v.y); u.z = f2bf(v.z); u.w = f2bf(v.w);
        ((ushort4*)y)[i] = u;
    }
}

// ---------------------------------------------------------------------------
// bf16 MFMA GEMM: C[M,512] = A[M,K] @ Bt[512,K]^T + bias (+res fp32).
// 128x128 tile, BK=32, 4 waves (64x64 each, 4x4 MFMA grid).
// 2-phase double-buffered pipeline: stage(t+1) issued BEFORE compute(t),
// one barrier per K-step (its auto vmcnt-drain lands after MFMA phase).
// 1-D grid, bijective chunked XCD swizzle (nwg % 8 == 0) so the 4
// col-blocks sharing an A-panel run on the same XCD (A L2-reuse).
// M%128==0, K%32==0. res may alias Cf (element-wise read-then-write).
// GELU: Cb=gelu(v) bf16, Cf=v fp32. Else WBF: Cb=bf16(v). WF32: Cf=v.
// ---------------------------------------------------------------------------
template<bool RES, bool GELU, bool WF32, bool WBF>
__global__ __launch_bounds__(256) void gemm_bf16(
    const bfbits* __restrict__ A, const bfbits* __restrict__ Bt,
    const float* __restrict__ bias, const float* res,
    float* Cf, bfbits* __restrict__ Cb, int M, int K)
{
    constexpr int N = 512;
    __shared__ __attribute__((aligned(16))) bfbits As[2][128 * 32];
    __shared__ __attribute__((aligned(16))) bfbits Bs[2][128 * 32];
    const int tid  = threadIdx.x;
    const int wave = tid >> 6, lane = tid & 63;

    // chunked XCD swizzle: o%8 = presumed XCD -> contiguous logical range
    const int nwg = gridDim.x;
    const int o = blockIdx.x;
    const int qch = nwg >> 3;                  // nwg % 8 == 0
    const int lg = (o & 7) * qch + (o >> 3);
    const int m0 = (lg >> 2) * 128, n0 = (lg & 3) * 128;

    const int wm = (wave >> 1) * 64, wn = (wave & 1) * 64;
    const int lr = lane & 15, quad = lane >> 4;

    floatx4 acc[4][4];
    #pragma unroll
    for (int i = 0; i < 4; ++i)
        #pragma unroll
        for (int j = 0; j < 4; ++j) acc[i][j] = 0.0f;

    // per-lane source row/col offset for staging (chunk c: rows c*16+(lane>>2))
    const int srow = lane >> 2;            // 0..15
    const int skof = (lane & 3) * 8;       // 0,8,16,24

    auto stage = [&](int buf, int k0) {
        #pragma unroll
        for (int i = 0; i < 2; ++i) {
            const int c = wave * 2 + i;             // chunk 0..7, uniform in wave
            const int row = c * 16 + srow;
            const bfbits* ga = A + (size_t)(m0 + row) * K + k0 + skof;
            const bfbits* gb = Bt + (size_t)(n0 + row) * K + k0 + skof;
            __builtin_amdgcn_global_load_lds(
                (const __attribute__((address_space(1))) void*)ga,
                (__attribute__((address_space(3))) void*)(&As[buf][c * 512]), 16, 0, 0);
            __builtin_amdgcn_global_load_lds(
                (const __attribute__((address_space(1))) void*)gb,
                (__attribute__((address_space(3))) void*)(&Bs[buf][c * 512]), 16, 0, 0);
        }
    };

    const int nt = K >> 5;
    stage(0, 0);
    __syncthreads();
    int cur = 0;
    for (int t = 0; t < nt; ++t) {
        if (t + 1 < nt) stage(cur ^ 1, (t + 1) * 32);   // prefetch next tile

        short8 af[4], bfv[4];
        #pragma unroll
        for (int i = 0; i < 4; ++i) {
            af[i]  = *(const short8*)(&As[cur][(wm + i * 16 + lr) * 32 + quad * 8]);
            bfv[i] = *(const short8*)(&Bs[cur][(wn + i * 16 + lr) * 32 + quad * 8]);
        }
        #pragma unroll
        for (int i = 0; i < 4; ++i)
            #pragma unroll
            for (int j = 0; j < 4; ++j)
                acc[i][j] = __builtin_amdgcn_mfma_f32_16x16x32_bf16(
                    af[i], bfv[j], acc[i][j], 0, 0, 0);

        __syncthreads();   // drains vmcnt (prefetch landed) + lgkm; publishes buffers
        cur ^= 1;
    }

    #pragma unroll
    for (int i = 0; i < 4; ++i) {
        #pragma unroll
        for (int j = 0; j < 4; ++j) {
            const int gc = n0 + wn + j * 16 + lr;
            const float bv = bias[gc];
            #pragma unroll
            for (int r = 0; r < 4; ++r) {
                const int gm = m0 + wm + i * 16 + quad * 4 + r;
                float v = acc[i][j][r] + bv;
                if (RES) v += res[(size_t)gm * N + gc];
                if (WF32) Cf[(size_t)gm * N + gc] = v;
                if (GELU) Cb[(size_t)gm * N + gc] = f2bf(gelu_exact(v));
                else if (WBF) Cb[(size_t)gm * N + gc] = f2bf(v);
            }
        }
    }
}

// ---------------------------------------------------------------------------
// Row LayerNorm over D=512; writes fp32 + bf16 copies.
// ---------------------------------------------------------------------------
__global__ __launch_bounds__(256) void ln2_kernel(
    const float* __restrict__ h, const float* __restrict__ g,
    const float* __restrict__ be, float* __restrict__ outf,
    bfbits* __restrict__ outb)
{
    __shared__ float red[256];
    const int row = blockIdx.x;
    const int tid = threadIdx.x;
    float v0 = h[(size_t)row * D_ + tid];
    float v1 = h[(size_t)row * D_ + 256 + tid];
    red[tid] = v0 + v1;
    __syncthreads();
    for (int s = 128; s > 0; s >>= 1) {
        if (tid < s) red[tid] += red[tid + s];
        __syncthreads();
    }
    float mu = red[0] * (1.0f / 512.0f);
    __syncthreads();
    float d0 = v0 - mu, d1 = v1 - mu;
    red[tid] = d0 * d0 + d1 * d1;
    __syncthreads();
    for (int s = 128; s > 0; s >>= 1) {
        if (tid < s) red[tid] += red[tid + s];
        __syncthreads();
    }
    float var = red[0] * (1.0f / 512.0f);
    float sc = rsqrtf(var + 1e-5f);
    float o0 = g[tid] * d0 * sc + be[tid];
    float o1 = g[256 + tid] * d1 * sc + be[256 + tid];
    outf[(size_t)row * D_ + tid]       = o0;
    outf[(size_t)row * D_ + 256 + tid] = o1;
    outb[(size_t)row * D_ + tid]       = f2bf(o0);
    outb[(size_t)row * D_ + 256 + tid] = f2bf(o1);
}

// ---------------------------------------------------------------------------
// Fused attention: one block per batch b, one wave per head.
// QK^T via MFMA computing S^T[ki][qi] = sum_d K[ki][d]*Q[qi][d]  (both row
// reads). Softmax over ki is lane-local(16 vals)+shfl_xor(16,32). P (fp32)
// goes to LDS; aw computed in-block; PV stays scalar (V reads coalesced).
// Padded tiles (49->64, 50->64) read workspace slack, masked to -inf / cut.
// ---------------------------------------------------------------------------
__global__ __launch_bounds__(256) void attn_kernel(
    const bfbits* __restrict__ q, const bfbits* __restrict__ k,
    const bfbits* __restrict__ v, bfbits* __restrict__ o,
    float* __restrict__ aw)
{
    constexpr int ROWF = 69;               // fp32 row stride (banks: 5*qi%32)
    __shared__ float sc[H_][SQ_ * ROWF];   // 54,096 B total
    const int b = blockIdx.x;
    const int tid = threadIdx.x;
    const int h = tid >> 6, lane = tid & 63;
    const int lr = lane & 15, g = lane >> 4;

    const bfbits* kb = k + ((size_t)b * SK_) * D_ + h * DH_;
    const bfbits* qb = q + ((size_t)b * SQ_) * D_ + h * DH_;

    // ---- S^T = K @ Q^T  (64x64 padded, 16 tiles, K-dim 128 = 4 steps) ----
    floatx4 acc[4][4];
    #pragma unroll
    for (int mi = 0; mi < 4; ++mi)
        #pragma unroll
        for (int ni = 0; ni < 4; ++ni) acc[mi][ni] = 0.0f;

    #pragma unroll
    for (int ks = 0; ks < 4; ++ks) {
        short8 afr[4], bfr[4];
        #pragma unroll
        for (int mi = 0; mi < 4; ++mi)
            afr[mi] = *(const short8*)(kb + (size_t)(mi * 16 + lr) * D_ + ks * 32 + g * 8);
        #pragma unroll
        for (int ni = 0; ni < 4; ++ni)
            bfr[ni] = *(const short8*)(qb + (size_t)(ni * 16 + lr) * D_ + ks * 32 + g * 8);
        #pragma unroll
        for (int mi = 0; mi < 4; ++mi)
            #pragma unroll
            for (int ni = 0; ni < 4; ++ni)
                acc[mi][ni] = __builtin_amdgcn_mfma_f32_16x16x32_bf16(
                    afr[mi], bfr[ni], acc[mi][ni], 0, 0, 0);
    }

    // ---- softmax over ki (rows of S^T) per qi column; write P to LDS ----
    const float scale = 0.08838834764831845f;   // 1/sqrt(128)
    #pragma unroll
    for (int ni = 0; ni < 4; ++ni) {
        const int qi = ni * 16 + lr;
        float mx = -1e30f;
        #pragma unroll
        for (int mi = 0; mi < 4; ++mi)
            #pragma unroll
            for (int r = 0; r < 4; ++r) {
                const int ki = mi * 16 + g * 4 + r;
                float s = (ki < SK_) ? acc[mi][ni][r] * scale : -1e30f;
                acc[mi][ni][r] = s;
                mx = fmaxf(mx, s);
            }
        mx = fmaxf(mx, __shfl_xor(mx, 16));
        mx = fmaxf(mx, __shfl_xor(mx, 32));
        float sum = 0.f;
        #pragma unroll
        for (int mi = 0; mi < 4; ++mi)
            #pragma unroll
            for (int r = 0; r < 4; ++r) {
                float ev = __expf(acc[mi][ni][r] - mx);  // masked -> exp(-inf)=0
                acc[mi][ni][r] = ev;
                sum += ev;
            }
        sum += __shfl_xor(sum, 16);
        sum += __shfl_xor(sum, 32);
        const float inv = 1.0f / sum;
        if (qi < SQ_) {
            #pragma unroll
            for (int mi = 0; mi < 4; ++mi) {
                float4 w;
                w.x = acc[mi][ni][0] * inv;
                w.y = acc[mi][ni][1] * inv;
                w.z = acc[mi][ni][2] * inv;
                w.w = acc[mi][ni][3] * inv;
                *(float4*)&sc[h][qi * ROWF + mi * 16 + g * 4] = w;
            }
        }
    }
    __syncthreads();

    // ---- aw[b,qi,ki] = 0.25 * sum_h P ----
    for (int e = tid; e < SQ_ * SK_; e += 256) {
        int qi = e / SK_, ki = e - qi * SK_;
        const int off = qi * ROWF + ki;
        aw[(size_t)b * (SQ_ * SK_) + e] =
            0.25f * (sc[0][off] + sc[1][off] + sc[2][off] + sc[3][off]);
    }

    // ---- PV: scalar fp32, V reads coalesced (L1/L2 resident) ----
    const bfbits* vb = v + ((size_t)b * SK_) * D_ + h * DH_;
    bfbits* ob = o + ((size_t)b * SQ_) * D_ + h * DH_;
    for (int e = lane; e < SQ_ * 16; e += 64) {
        const int qi = e >> 4, dc = e & 15;      // 8 d-elems per chunk
        const float* sr = &sc[h][qi * ROWF];
        float s[8] = {0.f, 0.f, 0.f, 0.f, 0.f, 0.f, 0.f, 0.f};
        for (int ki = 0; ki < SK_; ++ki) {
            const float a = sr[ki];
            short8 u = *(const short8*)(vb + (size_t)ki * D_ + dc * 8);
            #pragma unroll
            for (int j = 0; j < 8; ++j)
                s[j] = fmaf(a, bf2f((bfbits)u[j]), s[j]);
        }
        short8 ov;
        #pragma unroll
        for (int j = 0; j < 8; ++j) ov[j] = (short)f2bf(s[j]);
        *(short8*)(ob + (size_t)qi * D_ + dc * 8) = ov;
    }
}

// ---------------------------------------------------------------------------
// avg_attn -> n1; cls -> n2 (fp32)
// ---------------------------------------------------------------------------
__global__ __launch_bounds__(256) void norm_kernel(
    const float* __restrict__ ao, const float* __restrict__ pt,
    float* __restrict__ n1, float* __restrict__ n2)
{
    __shared__ float red[256];
    const int b = blockIdx.x, tid = threadIdx.x;
    float s0 = 0.f, s1 = 0.f;
    for (int s = 0; s < SQ_; ++s) {
        s0 += ao[((size_t)(b * SQ_ + s)) * D_ + tid];
        s1 += ao[((size_t)(b * SQ_ + s)) * D_ + 256 + tid];
    }
    s0 *= (1.0f / 49.0f);
    s1 *= (1.0f / 49.0f);
    red[tid] = s0 * s0 + s1 * s1;
    __syncthreads();
    for (int st = 128; st > 0; st >>= 1) {
        if (tid < st) red[tid] += red[tid + st];
        __syncthreads();
    }
    float inv = rsqrtf(red[0]);
    __syncthreads();
    n1[(size_t)b * D_ + tid] = s0 * inv;
    n1[(size_t)b * D_ + 256 + tid] = s1 * inv;

    float c0 = pt[((size_t)(b * SK_)) * D_ + tid];
    float c1 = pt[((size_t)(b * SK_)) * D_ + 256 + tid];
    red[tid] = c0 * c0 + c1 * c1;
    __syncthreads();
    for (int st = 128; st > 0; st >>= 1) {
        if (tid < st) red[tid] += red[tid + st];
        __syncthreads();
    }
    float inv2 = rsqrtf(red[0]);
    n2[(size_t)b * D_ + tid] = c0 * inv2;
    n2[(size_t)b * D_ + 256 + tid] = c1 * inv2;
}

// ---------------------------------------------------------------------------
// fp32 score GEMM: C[512,512] = n1[512,512] @ n2[512,512]^T  (tiny)
// ---------------------------------------------------------------------------
__global__ __launch_bounds__(256) void score_gemm(
    const float* __restrict__ A, const float* __restrict__ Bm,
    float* __restrict__ C)
{
    const int BM = 64, BN = 64, BK = 16, Kt = 512, Nt = 512;
    __shared__ float As[BK][BM + 1];
    __shared__ float Bs[BK][BN + 1];
    const int tid = threadIdx.x;
    const int m0 = blockIdx.y * BM, n0 = blockIdx.x * BN;
    const int tc = tid & 15, tr = tid >> 4;
    float acc[4][4] = {};
    for (int k0 = 0; k0 < Kt; k0 += BK) {
        #pragma unroll
        for (int i = 0; i < 4; ++i) {
            int idx = tid + i * 256;
            int m = idx >> 4, kk = idx & 15;
            As[kk][m] = A[(size_t)(m0 + m) * Kt + k0 + kk];
            Bs[kk][m] = Bm[(size_t)(n0 + m) * Kt + k0 + kk];
        }
        __syncthreads();
        #pragma unroll
        for (int kk = 0; kk < BK; ++kk) {
            float a4[4], b4[4];
            #pragma unroll
            for (int i = 0; i < 4; ++i) a4[i] = As[kk][tr * 4 + i];
            #pragma unroll
            for (int j = 0; j < 4; ++j) b4[j] = Bs[kk][tc * 4 + j];
            #pragma unroll
            for (int i = 0; i < 4; ++i)
                #pragma unroll
                for (int j = 0; j < 4; ++j)
                    acc[i][j] = fmaf(a4[i], b4[j], acc[i][j]);
        }
        __syncthreads();
    }
    #pragma unroll
    for (int i = 0; i < 4; ++i)
        #pragma unroll
        for (int j = 0; j < 4; ++j)
            C[(size_t)(m0 + tr * 4 + i) * Nt + n0 + tc * 4 + j] = acc[i][j];
}

extern "C" void kernel_launch(void* const* d_in, const int* in_sizes, int n_in,
                              void* d_out, int out_size, void* d_ws, size_t ws_size,
                              hipStream_t stream)
{
    const float* img = (const float*)d_in[0];
    const float* txt = (const float*)d_in[1];
    const float* Wi1 = (const float*)d_in[2];  const float* bi1 = (const float*)d_in[3];
    const float* Wi2 = (const float*)d_in[4];  const float* bi2 = (const float*)d_in[5];
    const float* gi  = (const float*)d_in[6];  const float* bei = (const float*)d_in[7];
    const float* Wt1 = (const float*)d_in[8];  const float* bt1 = (const float*)d_in[9];
    const float* Wt2 = (const float*)d_in[10]; const float* bt2 = (const float*)d_in[11];
    const float* gt  = (const float*)d_in[12]; const float* bet = (const float*)d_in[13];
    const float* Wq  = (const float*)d_in[14]; const float* bq  = (const float*)d_in[15];
    const float* Wk  = (const float*)d_in[16]; const float* bk  = (const float*)d_in[17];
    const float* Wv  = (const float*)d_in[18]; const float* bv  = (const float*)d_in[19];
    const float* Wo  = (const float*)d_in[20]; const float* bo  = (const float*)d_in[21];
    float* out = (float*)d_out;

    // ---- workspace layout (~230 MiB) ----
    bfbits* Wi1T = (bfbits*)d_ws;                 // 2048*512
    bfbits* Wi2T = Wi1T + 1048576;                // 512*512
    bfbits* Wt1T = Wi2T + 262144;                 // 768*512
    bfbits* Wt2T = Wt1T + 393216;
    bfbits* WqT  = Wt2T + 262144;
    bfbits* WkT  = WqT  + 262144;
    bfbits* WvT  = WkT  + 262144;
    bfbits* WoT  = WvT  + 262144;
    bfbits* R1   = WoT  + 262144;                 // 51,380,224 bf16 elems
    bfbits* Aimg = R1;                            // 25088*2048
    bfbits* Atxt = R1;                            // 25600*768 (after img phase)
    bfbits* Qbf  = R1 + 20000000;                 // 25088*512
    bfbits* Kbf  = R1 + 33200000;                 // 25600*512
    float*  R2   = (float*)(R1 + 51380224);       // 13,107,200 floats (P/H)
    bfbits* Vbf  = (bfbits*)R2;                   // 25600*512 (after H dead)
    bfbits* R3   = (bfbits*)(R2 + 13107200);      // 13,107,200 bf16 (G / Obf)
    bfbits* Obf  = R3;
    bfbits* PiBf = R3 + 13107200;                 // 25088*512
    bfbits* PtBf = PiBf + 12845056;               // 25600*512
    float*  n1   = (float*)(PtBf + 13107200);
    float*  n2   = n1 + 262144;

    const int MI = B_ * SQ_;   // 25088
    const int MT = B_ * SK_;   // 25600
    dim3 blk(256);

    // weights -> transposed bf16
    wcast_t<<<dim3(DIMG_ / 32, D_ / 32), blk, 0, stream>>>(Wi1, Wi1T, DIMG_, D_);
    wcast_t<<<dim3(D_ / 32, D_ / 32),    blk, 0, stream>>>(Wi2, Wi2T, D_, D_);
    wcast_t<<<dim3(DTXT_ / 32, D_ / 32), blk, 0, stream>>>(Wt1, Wt1T, DTXT_, D_);
    wcast_t<<<dim3(D_ / 32, D_ / 32),    blk, 0, stream>>>(Wt2, Wt2T, D_, D_);
    wcast_t<<<dim3(D_ / 32, D_ / 32),    blk, 0, stream>>>(Wq, WqT, D_, D_);
    wcast_t<<<dim3(D_ / 32, D_ / 32),    blk, 0, stream>>>(Wk, WkT, D_, D_);
    wcast_t<<<dim3(D_ / 32, D_ / 32),    blk, 0, stream>>>(Wv, WvT, D_, D_);
    wcast_t<<<dim3(D_ / 32, D_ / 32),    blk, 0, stream>>>(Wo, WoT, D_, D_);

    // ---- image head ----  (1-D grids: nwg = 4 * M/128, all % 8 == 0)
    img_t<<<dim3(DIMG_ / 64, B_), blk, 0, stream>>>(img, Aimg);
    gemm_bf16<false, true, true, true><<<dim3(4 * (MI / 128)), blk, 0, stream>>>(
        Aimg, Wi1T, bi1, nullptr, R2, R3, MI, DIMG_);            // p fp32 + gelu bf16
    gemm_bf16<true, false, true, false><<<dim3(4 * (MI / 128)), blk, 0, stream>>>(
        R3, Wi2T, bi2, R2, R2, nullptr, MI, D_);                 // h = g@W2+b2+p (in-place)
    ln2_kernel<<<dim3(MI), blk, 0, stream>>>(R2, gi, bei, out + PI_OFF, PiBf);

    // ---- text head ----
    cast4<<<dim3((MT * DTXT_ / 4 + 255) / 256), blk, 0, stream>>>(txt, Atxt, MT * DTXT_ / 4);
    gemm_bf16<false, true, true, true><<<dim3(4 * (MT / 128)), blk, 0, stream>>>(
        Atxt, Wt1T, bt1, nullptr, R2, R3, MT, DTXT_);
    gemm_bf16<true, false, true, false><<<dim3(4 * (MT / 128)), blk, 0, stream>>>(
        R3, Wt2T, bt2, R2, R2, nullptr, MT, D_);
    ln2_kernel<<<dim3(MT), blk, 0, stream>>>(R2, gt, bet, out + PT_OFF, PtBf);

    // ---- q, k, v (bf16 out) ----
    gemm_bf16<false, false, false, true><<<dim3(4 * (MI / 128)), blk, 0, stream>>>(
        PiBf, WqT, bq, nullptr, nullptr, Qbf, MI, D_);
    gemm_bf16<false, false, false, true><<<dim3(4 * (MT / 128)), blk, 0, stream>>>(
        PtBf, WkT, bk, nullptr, nullptr, Kbf, MT, D_);
    gemm_bf16<false, false, false, true><<<dim3(4 * (MT / 128)), blk, 0, stream>>>(
        PtBf, WvT, bv, nullptr, nullptr, Vbf, MT, D_);

    // ---- attention: one block per batch, one wave per head ----
    attn_kernel<<<dim3(B_), blk, 0, stream>>>(Qbf, Kbf, Vbf, Obf, out + AW_OFF);

    // ---- output projection ----
    gemm_bf16<false, false, true, false><<<dim3(4 * (MI / 128)), blk, 0, stream>>>(
        Obf, WoT, bo, nullptr, out + AO_OFF, nullptr, MI, D_);

    // ---- similarity score ----
    norm_kernel<<<dim3(B_), blk, 0, stream>>>(out + AO_OFF, out + PT_OFF, n1, n2);
    score_gemm<<<dim3(8, 8), blk, 0, stream>>>(n1, n2, out + SCORE_OFF);
}

// Round 4
// 1041.276 us; speedup vs baseline: 1.2247x; 1.0071x over previous
//
#include <hip/hip_runtime.h>
#include <math.h>

#define B_    512
#define SQ_   49
#define SK_   50
#define DIMG_ 2048
#define DTXT_ 768
#define D_    512
#define H_    4
#define DH_   128

// output offsets (floats): score, attn_output, attn_weights, pi, pt
#define SCORE_OFF 0
#define AO_OFF    262144      // 512*512
#define AW_OFF    13107200    // + 512*49*512
#define PI_OFF    14361600    // + 512*49*50
#define PT_OFF    27206656    // + 512*49*512

typedef unsigned short bfbits;
typedef __attribute__((ext_vector_type(8))) short short8;
typedef __attribute__((ext_vector_type(4))) float floatx4;

static __device__ __forceinline__ bfbits f2bf(float f) {
    union { float f; unsigned u; } a; a.f = f;
    return (bfbits)((a.u + 0x7fffu + ((a.u >> 16) & 1u)) >> 16);
}
static __device__ __forceinline__ float bf2f(bfbits b) {
    union { unsigned u; float f; } a; a.u = ((unsigned)b) << 16;
    return a.f;
}
static __device__ __forceinline__ float gelu_exact(float x) {
    return 0.5f * x * (1.0f + erff(x * 0.70710678118654752f));
}

// ---------------------------------------------------------------------------
// Weight transpose+cast: W (K,N) fp32 -> Wt (N,K) bf16.  K,N % 32 == 0.
// ---------------------------------------------------------------------------
__global__ __launch_bounds__(256) void wcast_t(
    const float* __restrict__ W, bfbits* __restrict__ Wt, int K, int N)
{
    __shared__ float t[32][33];
    const int k0 = blockIdx.x * 32, n0 = blockIdx.y * 32;
    const int tx = threadIdx.x & 31, ty = threadIdx.x >> 5;  // 32 x 8
    #pragma unroll
    for (int i = 0; i < 32; i += 8)
        t[ty + i][tx] = W[(size_t)(k0 + ty + i) * N + n0 + tx];
    __syncthreads();
    #pragma unroll
    for (int i = 0; i < 32; i += 8)
        Wt[(size_t)(n0 + ty + i) * K + k0 + tx] = f2bf(t[tx][ty + i]);
}

// ---------------------------------------------------------------------------
// Image transpose+cast: img[b, k, s] fp32 -> A[(b*49+s), k] bf16 (K=2048)
// block = (k-tile of 64, b)
// ---------------------------------------------------------------------------
__global__ __launch_bounds__(256) void img_t(
    const float* __restrict__ img, bfbits* __restrict__ A)
{
    __shared__ float t[64][50];
    const int b = blockIdx.y, k0 = blockIdx.x * 64;
    const float* src = img + (size_t)b * (DIMG_ * SQ_) + (size_t)k0 * SQ_;
    for (int e = threadIdx.x; e < 64 * 49; e += 256) {
        int kl = e / 49, s = e - kl * 49;
        t[kl][s] = src[kl * 49 + s];
    }
    __syncthreads();
    bfbits* dst = A + (size_t)b * SQ_ * DIMG_ + k0;
    for (int e = threadIdx.x; e < 49 * 64; e += 256) {
        int s = e >> 6, kl = e & 63;
        dst[(size_t)s * DIMG_ + kl] = f2bf(t[kl][s]);
    }
}

// ---------------------------------------------------------------------------
// Flat fp32 -> bf16 cast, 4 elements/thread. n % 4 == 0.
// ---------------------------------------------------------------------------
__global__ __launch_bounds__(256) void cast4(
    const float* __restrict__ x, bfbits* __restrict__ y, int n4)
{
    int i = blockIdx.x * 256 + threadIdx.x;
    if (i < n4) {
        float4 v = ((const float4*)x)[i];
        ushort4 u;
        u.x = f2bf(v.x); u.y = f2bf(v.y); u.z = f2bf(v.z); u.w = f2bf(v.w);
        ((ushort4*)y)[i] = u;
    }
}

// ---------------------------------------------------------------------------
// bf16 MFMA GEMM: C[M,512] = A[M,K] @ Bt[512,K]^T + bias (+res fp32).
// 128x128 tile, BK=32, 4 waves (64x64 each, 4x4 MFMA grid).
// 3-buffer, 3-deep prefetch pipeline with COUNTED vmcnt (T3+T4):
//   wait vmcnt(8) -> barrier -> ds_read -> lgkmcnt(0) -> barrier ->
//   restage freed buffer (race-free by construction) -> MFMA (setprio).
// Loads for 2 future tiles stay in flight across barriers; never drain to
// vmcnt(0) in steady state.  1-D grid, bijective chunked XCD swizzle
// (nwg % 8 == 0): 4 col-blocks sharing an A-panel run on one XCD.
// M%128==0, K%32==0, K>=96. res may alias Cf (elementwise read-then-write).
// GELU: Cb=gelu(v) bf16, Cf=v fp32. Else WBF: Cb=bf16(v). WF32: Cf=v.
// ---------------------------------------------------------------------------
template<bool RES, bool GELU, bool WF32, bool WBF>
__global__ __launch_bounds__(256) void gemm_bf16(
    const bfbits* __restrict__ A, const bfbits* __restrict__ Bt,
    const float* __restrict__ bias, const float* res,
    float* Cf, bfbits* __restrict__ Cb, int M, int K)
{
    constexpr int N = 512;
    __shared__ __attribute__((aligned(16))) bfbits As[3][128 * 32];
    __shared__ __attribute__((aligned(16))) bfbits Bs[3][128 * 32];
    const int tid  = threadIdx.x;
    const int wave = tid >> 6, lane = tid & 63;

    // chunked XCD swizzle: o%8 = presumed XCD -> contiguous logical range
    const int nwg = gridDim.x;
    const int o = blockIdx.x;
    const int qch = nwg >> 3;                  // nwg % 8 == 0
    const int lg = (o & 7) * qch + (o >> 3);
    const int m0 = (lg >> 2) * 128, n0 = (lg & 3) * 128;

    const int wm = (wave >> 1) * 64, wn = (wave & 1) * 64;
    const int lr = lane & 15, quad = lane >> 4;

    floatx4 acc[4][4];
    #pragma unroll
    for (int i = 0; i < 4; ++i)
        #pragma unroll
        for (int j = 0; j < 4; ++j) acc[i][j] = 0.0f;

    // per-lane source row/col offset for staging (chunk c: rows c*16+(lane>>2))
    const int srow = lane >> 2;            // 0..15
    const int skof = (lane & 3) * 8;       // 0,8,16,24

    // one stage = 4 global_load_lds per lane (2 chunks x {A,B})
    auto stage = [&](int buf, int t) {
        const int k0 = t * 32;
        #pragma unroll
        for (int i = 0; i < 2; ++i) {
            const int c = wave * 2 + i;             // chunk 0..7, uniform in wave
            const int row = c * 16 + srow;
            const bfbits* ga = A + (size_t)(m0 + row) * K + k0 + skof;
            const bfbits* gb = Bt + (size_t)(n0 + row) * K + k0 + skof;
            __builtin_amdgcn_global_load_lds(
                (const __attribute__((address_space(1))) void*)ga,
                (__attribute__((address_space(3))) void*)(&As[buf][c * 512]), 16, 0, 0);
            __builtin_amdgcn_global_load_lds(
                (const __attribute__((address_space(1))) void*)gb,
                (__attribute__((address_space(3))) void*)(&Bs[buf][c * 512]), 16, 0, 0);
        }
    };

    const int nt = K >> 5;                 // >= 3 always here (K >= 512)
    stage(0, 0);
    stage(1, 1);
    stage(2, 2);                           // 12 loads/lane outstanding

    int cur = 0;
    for (int t = 0; t < nt; ++t) {
        // wait until stage t has landed; keep later stages in flight
        const int left = nt - 1 - t;
        if (left >= 2)      asm volatile("s_waitcnt vmcnt(8)" ::: "memory");
        else if (left == 1) asm volatile("s_waitcnt vmcnt(4)" ::: "memory");
        else                asm volatile("s_waitcnt vmcnt(0)" ::: "memory");
        __builtin_amdgcn_s_barrier();      // buf[cur] ready for all waves

        short8 af[4], bfv[4];
        #pragma unroll
        for (int i = 0; i < 4; ++i) {
            af[i]  = *(const short8*)(&As[cur][(wm + i * 16 + lr) * 32 + quad * 8]);
            bfv[i] = *(const short8*)(&Bs[cur][(wn + i * 16 + lr) * 32 + quad * 8]);
        }
        asm volatile("s_waitcnt lgkmcnt(0)" ::: "memory");
        __builtin_amdgcn_s_barrier();      // all waves done reading buf[cur]

        if (t + 3 < nt) stage(cur, t + 3); // refill freed buffer (post-barrier: safe)

        __builtin_amdgcn_s_setprio(1);
        #pragma unroll
        for (int i = 0; i < 4; ++i)
            #pragma unroll
            for (int j = 0; j < 4; ++j)
                acc[i][j] = __builtin_amdgcn_mfma_f32_16x16x32_bf16(
                    af[i], bfv[j], acc[i][j], 0, 0, 0);
        __builtin_amdgcn_s_setprio(0);

        cur = (cur == 2) ? 0 : cur + 1;
    }

    #pragma unroll
    for (int i = 0; i < 4; ++i) {
        #pragma unroll
        for (int j = 0; j < 4; ++j) {
            const int gc = n0 + wn + j * 16 + lr;
            const float bv = bias[gc];
            #pragma unroll
            for (int r = 0; r < 4; ++r) {
                const int gm = m0 + wm + i * 16 + quad * 4 + r;
                float v = acc[i][j][r] + bv;
                if (RES) v += res[(size_t)gm * N + gc];
                if (WF32) Cf[(size_t)gm * N + gc] = v;
                if (GELU) Cb[(size_t)gm * N + gc] = f2bf(gelu_exact(v));
                else if (WBF) Cb[(size_t)gm * N + gc] = f2bf(v);
            }
        }
    }
}

// ---------------------------------------------------------------------------
// Row LayerNorm over D=512; writes fp32 + bf16 copies.
// ---------------------------------------------------------------------------
__global__ __launch_bounds__(256) void ln2_kernel(
    const float* __restrict__ h, const float* __restrict__ g,
    const float* __restrict__ be, float* __restrict__ outf,
    bfbits* __restrict__ outb)
{
    __shared__ float red[256];
    const int row = blockIdx.x;
    const int tid = threadIdx.x;
    float v0 = h[(size_t)row * D_ + tid];
    float v1 = h[(size_t)row * D_ + 256 + tid];
    red[tid] = v0 + v1;
    __syncthreads();
    for (int s = 128; s > 0; s >>= 1) {
        if (tid < s) red[tid] += red[tid + s];
        __syncthreads();
    }
    float mu = red[0] * (1.0f / 512.0f);
    __syncthreads();
    float d0 = v0 - mu, d1 = v1 - mu;
    red[tid] = d0 * d0 + d1 * d1;
    __syncthreads();
    for (int s = 128; s > 0; s >>= 1) {
        if (tid < s) red[tid] += red[tid + s];
        __syncthreads();
    }
    float var = red[0] * (1.0f / 512.0f);
    float sc = rsqrtf(var + 1e-5f);
    float o0 = g[tid] * d0 * sc + be[tid];
    float o1 = g[256 + tid] * d1 * sc + be[256 + tid];
    outf[(size_t)row * D_ + tid]       = o0;
    outf[(size_t)row * D_ + 256 + tid] = o1;
    outb[(size_t)row * D_ + tid]       = f2bf(o0);
    outb[(size_t)row * D_ + 256 + tid] = f2bf(o1);
}

// ---------------------------------------------------------------------------
// Fused attention: one block per batch b, one wave per head.
// QK^T via MFMA computing S^T[ki][qi] = sum_d K[ki][d]*Q[qi][d]  (both row
// reads). Softmax over ki is lane-local(16 vals)+shfl_xor(16,32). P (fp32)
// goes to LDS; aw computed in-block; PV stays scalar (V reads coalesced).
// Padded tiles (49->64, 50->64) read workspace slack, masked to -inf / cut.
// ---------------------------------------------------------------------------
__global__ __launch_bounds__(256) void attn_kernel(
    const bfbits* __restrict__ q, const bfbits* __restrict__ k,
    const bfbits* __restrict__ v, bfbits* __restrict__ o,
    float* __restrict__ aw)
{
    constexpr int ROWF = 69;               // fp32 row stride (banks: 5*qi%32)
    __shared__ float sc[H_][SQ_ * ROWF];   // 54,096 B total
    const int b = blockIdx.x;
    const int tid = threadIdx.x;
    const int h = tid >> 6, lane = tid & 63;
    const int lr = lane & 15, g = lane >> 4;

    const bfbits* kb = k + ((size_t)b * SK_) * D_ + h * DH_;
    const bfbits* qb = q + ((size_t)b * SQ_) * D_ + h * DH_;

    // ---- S^T = K @ Q^T  (64x64 padded, 16 tiles, K-dim 128 = 4 steps) ----
    floatx4 acc[4][4];
    #pragma unroll
    for (int mi = 0; mi < 4; ++mi)
        #pragma unroll
        for (int ni = 0; ni < 4; ++ni) acc[mi][ni] = 0.0f;

    #pragma unroll
    for (int ks = 0; ks < 4; ++ks) {
        short8 afr[4], bfr[4];
        #pragma unroll
        for (int mi = 0; mi < 4; ++mi)
            afr[mi] = *(const short8*)(kb + (size_t)(mi * 16 + lr) * D_ + ks * 32 + g * 8);
        #pragma unroll
        for (int ni = 0; ni < 4; ++ni)
            bfr[ni] = *(const short8*)(qb + (size_t)(ni * 16 + lr) * D_ + ks * 32 + g * 8);
        #pragma unroll
        for (int mi = 0; mi < 4; ++mi)
            #pragma unroll
            for (int ni = 0; ni < 4; ++ni)
                acc[mi][ni] = __builtin_amdgcn_mfma_f32_16x16x32_bf16(
                    afr[mi], bfr[ni], acc[mi][ni], 0, 0, 0);
    }

    // ---- softmax over ki (rows of S^T) per qi column; write P to LDS ----
    const float scale = 0.08838834764831845f;   // 1/sqrt(128)
    #pragma unroll
    for (int ni = 0; ni < 4; ++ni) {
        const int qi = ni * 16 + lr;
        float mx = -1e30f;
        #pragma unroll
        for (int mi = 0; mi < 4; ++mi)
            #pragma unroll
            for (int r = 0; r < 4; ++r) {
                const int ki = mi * 16 + g * 4 + r;
                float s = (ki < SK_) ? acc[mi][ni][r] * scale : -1e30f;
                acc[mi][ni][r] = s;
                mx = fmaxf(mx, s);
            }
        mx = fmaxf(mx, __shfl_xor(mx, 16));
        mx = fmaxf(mx, __shfl_xor(mx, 32));
        float sum = 0.f;
        #pragma unroll
        for (int mi = 0; mi < 4; ++mi)
            #pragma unroll
            for (int r = 0; r < 4; ++r) {
                float ev = __expf(acc[mi][ni][r] - mx);  // masked -> exp(-inf)=0
                acc[mi][ni][r] = ev;
                sum += ev;
            }
        sum += __shfl_xor(sum, 16);
        sum += __shfl_xor(sum, 32);
        const float inv = 1.0f / sum;
        if (qi < SQ_) {
            #pragma unroll
            for (int mi = 0; mi < 4; ++mi) {
                float4 w;
                w.x = acc[mi][ni][0] * inv;
                w.y = acc[mi][ni][1] * inv;
                w.z = acc[mi][ni][2] * inv;
                w.w = acc[mi][ni][3] * inv;
                *(float4*)&sc[h][qi * ROWF + mi * 16 + g * 4] = w;
            }
        }
    }
    __syncthreads();

    // ---- aw[b,qi,ki] = 0.25 * sum_h P ----
    for (int e = tid; e < SQ_ * SK_; e += 256) {
        int qi = e / SK_, ki = e - qi * SK_;
        const int off = qi * ROWF + ki;
        aw[(size_t)b * (SQ_ * SK_) + e] =
            0.25f * (sc[0][off] + sc[1][off] + sc[2][off] + sc[3][off]);
    }

    // ---- PV: scalar fp32, V reads coalesced (L1/L2 resident) ----
    const bfbits* vb = v + ((size_t)b * SK_) * D_ + h * DH_;
    bfbits* ob = o + ((size_t)b * SQ_) * D_ + h * DH_;
    for (int e = lane; e < SQ_ * 16; e += 64) {
        const int qi = e >> 4, dc = e & 15;      // 8 d-elems per chunk
        const float* sr = &sc[h][qi * ROWF];
        float s[8] = {0.f, 0.f, 0.f, 0.f, 0.f, 0.f, 0.f, 0.f};
        for (int ki = 0; ki < SK_; ++ki) {
            const float a = sr[ki];
            short8 u = *(const short8*)(vb + (size_t)ki * D_ + dc * 8);
            #pragma unroll
            for (int j = 0; j < 8; ++j)
                s[j] = fmaf(a, bf2f((bfbits)u[j]), s[j]);
        }
        short8 ov;
        #pragma unroll
        for (int j = 0; j < 8; ++j) ov[j] = (short)f2bf(s[j]);
        *(short8*)(ob + (size_t)qi * D_ + dc * 8) = ov;
    }
}

// ---------------------------------------------------------------------------
// avg_attn -> n1; cls -> n2 (fp32)
// ---------------------------------------------------------------------------
__global__ __launch_bounds__(256) void norm_kernel(
    const float* __restrict__ ao, const float* __restrict__ pt,
    float* __restrict__ n1, float* __restrict__ n2)
{
    __shared__ float red[256];
    const int b = blockIdx.x, tid = threadIdx.x;
    float s0 = 0.f, s1 = 0.f;
    for (int s = 0; s < SQ_; ++s) {
        s0 += ao[((size_t)(b * SQ_ + s)) * D_ + tid];
        s1 += ao[((size_t)(b * SQ_ + s)) * D_ + 256 + tid];
    }
    s0 *= (1.0f / 49.0f);
    s1 *= (1.0f / 49.0f);
    red[tid] = s0 * s0 + s1 * s1;
    __syncthreads();
    for (int st = 128; st > 0; st >>= 1) {
        if (tid < st) red[tid] += red[tid + st];
        __syncthreads();
    }
    float inv = rsqrtf(red[0]);
    __syncthreads();
    n1[(size_t)b * D_ + tid] = s0 * inv;
    n1[(size_t)b * D_ + 256 + tid] = s1 * inv;

    float c0 = pt[((size_t)(b * SK_)) * D_ + tid];
    float c1 = pt[((size_t)(b * SK_)) * D_ + 256 + tid];
    red[tid] = c0 * c0 + c1 * c1;
    __syncthreads();
    for (int st = 128; st > 0; st >>= 1) {
        if (tid < st) red[tid] += red[tid + st];
        __syncthreads();
    }
    float inv2 = rsqrtf(red[0]);
    n2[(size_t)b * D_ + tid] = c0 * inv2;
    n2[(size_t)b * D_ + 256 + tid] = c1 * inv2;
}

// ---------------------------------------------------------------------------
// fp32 score GEMM: C[512,512] = n1[512,512] @ n2[512,512]^T  (tiny)
// ---------------------------------------------------------------------------
__global__ __launch_bounds__(256) void score_gemm(
    const float* __restrict__ A, const float* __restrict__ Bm,
    float* __restrict__ C)
{
    const int BM = 64, BN = 64, BK = 16, Kt = 512, Nt = 512;
    __shared__ float As[BK][BM + 1];
    __shared__ float Bs[BK][BN + 1];
    const int tid = threadIdx.x;
    const int m0 = blockIdx.y * BM, n0 = blockIdx.x * BN;
    const int tc = tid & 15, tr = tid >> 4;
    float acc[4][4] = {};
    for (int k0 = 0; k0 < Kt; k0 += BK) {
        #pragma unroll
        for (int i = 0; i < 4; ++i) {
            int idx = tid + i * 256;
            int m = idx >> 4, kk = idx & 15;
            As[kk][m] = A[(size_t)(m0 + m) * Kt + k0 + kk];
            Bs[kk][m] = Bm[(size_t)(n0 + m) * Kt + k0 + kk];
        }
        __syncthreads();
        #pragma unroll
        for (int kk = 0; kk < BK; ++kk) {
            float a4[4], b4[4];
            #pragma unroll
            for (int i = 0; i < 4; ++i) a4[i] = As[kk][tr * 4 + i];
            #pragma unroll
            for (int j = 0; j < 4; ++j) b4[j] = Bs[kk][tc * 4 + j];
            #pragma unroll
            for (int i = 0; i < 4; ++i)
                #pragma unroll
                for (int j = 0; j < 4; ++j)
                    acc[i][j] = fmaf(a4[i], b4[j], acc[i][j]);
        }
        __syncthreads();
    }
    #pragma unroll
    for (int i = 0; i < 4; ++i)
        #pragma unroll
        for (int j = 0; j < 4; ++j)
            C[(size_t)(m0 + tr * 4 + i) * Nt + n0 + tc * 4 + j] = acc[i][j];
}

extern "C" void kernel_launch(void* const* d_in, const int* in_sizes, int n_in,
                              void* d_out, int out_size, void* d_ws, size_t ws_size,
                              hipStream_t stream)
{
    const float* img = (const float*)d_in[0];
    const float* txt = (const float*)d_in[1];
    const float* Wi1 = (const float*)d_in[2];  const float* bi1 = (const float*)d_in[3];
    const float* Wi2 = (const float*)d_in[4];  const float* bi2 = (const float*)d_in[5];
    const float* gi  = (const float*)d_in[6];  const float* bei = (const float*)d_in[7];
    const float* Wt1 = (const float*)d_in[8];  const float* bt1 = (const float*)d_in[9];
    const float* Wt2 = (const float*)d_in[10]; const float* bt2 = (const float*)d_in[11];
    const float* gt  = (const float*)d_in[12]; const float* bet = (const float*)d_in[13];
    const float* Wq  = (const float*)d_in[14]; const float* bq  = (const float*)d_in[15];
    const float* Wk  = (const float*)d_in[16]; const float* bk  = (const float*)d_in[17];
    const float* Wv  = (const float*)d_in[18]; const float* bv  = (const float*)d_in[19];
    const float* Wo  = (const float*)d_in[20]; const float* bo  = (const float*)d_in[21];
    float* out = (float*)d_out;

    // ---- workspace layout (~230 MiB) ----
    bfbits* Wi1T = (bfbits*)d_ws;                 // 2048*512
    bfbits* Wi2T = Wi1T + 1048576;                // 512*512
    bfbits* Wt1T = Wi2T + 262144;                 // 768*512
    bfbits* Wt2T = Wt1T + 393216;
    bfbits* WqT  = Wt2T + 262144;
    bfbits* WkT  = WqT  + 262144;
    bfbits* WvT  = WkT  + 262144;
    bfbits* WoT  = WvT  + 262144;
    bfbits* R1   = WoT  + 262144;                 // 51,380,224 bf16 elems
    bfbits* Aimg = R1;                            // 25088*2048
    bfbits* Atxt = R1;                            // 25600*768 (after img phase)
    bfbits* Qbf  = R1 + 20000000;                 // 25088*512
    bfbits* Kbf  = R1 + 33200000;                 // 25600*512
    float*  R2   = (float*)(R1 + 51380224);       // 13,107,200 floats (P/H)
    bfbits* Vbf  = (bfbits*)R2;                   // 25600*512 (after H dead)
    bfbits* R3   = (bfbits*)(R2 + 13107200);      // 13,107,200 bf16 (G / Obf)
    bfbits* Obf  = R3;
    bfbits* PiBf = R3 + 13107200;                 // 25088*512
    bfbits* PtBf = PiBf + 12845056;               // 25600*512
    float*  n1   = (float*)(PtBf + 13107200);
    float*  n2   = n1 + 262144;

    const int MI = B_ * SQ_;   // 25088
    const int MT = B_ * SK_;   // 25600
    dim3 blk(256);

    // weights -> transposed bf16
    wcast_t<<<dim3(DIMG_ / 32, D_ / 32), blk, 0, stream>>>(Wi1, Wi1T, DIMG_, D_);
    wcast_t<<<dim3(D_ / 32, D_ / 32),    blk, 0, stream>>>(Wi2, Wi2T, D_, D_);
    wcast_t<<<dim3(DTXT_ / 32, D_ / 32), blk, 0, stream>>>(Wt1, Wt1T, DTXT_, D_);
    wcast_t<<<dim3(D_ / 32, D_ / 32),    blk, 0, stream>>>(Wt2, Wt2T, D_, D_);
    wcast_t<<<dim3(D_ / 32, D_ / 32),    blk, 0, stream>>>(Wq, WqT, D_, D_);
    wcast_t<<<dim3(D_ / 32, D_ / 32),    blk, 0, stream>>>(Wk, WkT, D_, D_);
    wcast_t<<<dim3(D_ / 32, D_ / 32),    blk, 0, stream>>>(Wv, WvT, D_, D_);
    wcast_t<<<dim3(D_ / 32, D_ / 32),    blk, 0, stream>>>(Wo, WoT, D_, D_);

    // ---- image head ----  (1-D grids: nwg = 4 * M/128, all % 8 == 0)
    img_t<<<dim3(DIMG_ / 64, B_), blk, 0, stream>>>(img, Aimg);
    gemm_bf16<false, true, true, true><<<dim3(4 * (MI / 128)), blk, 0, stream>>>(
        Aimg, Wi1T, bi1, nullptr, R2, R3, MI, DIMG_);            // p fp32 + gelu bf16
    gemm_bf16<true, false, true, false><<<dim3(4 * (MI / 128)), blk, 0, stream>>>(
        R3, Wi2T, bi2, R2, R2, nullptr, MI, D_);                 // h = g@W2+b2+p (in-place)
    ln2_kernel<<<dim3(MI), blk, 0, stream>>>(R2, gi, bei, out + PI_OFF, PiBf);

    // ---- text head ----
    cast4<<<dim3((MT * DTXT_ / 4 + 255) / 256), blk, 0, stream>>>(txt, Atxt, MT * DTXT_ / 4);
    gemm_bf16<false, true, true, true><<<dim3(4 * (MT / 128)), blk, 0, stream>>>(
        Atxt, Wt1T, bt1, nullptr, R2, R3, MT, DTXT_);
    gemm_bf16<true, false, true, false><<<dim3(4 * (MT / 128)), blk, 0, stream>>>(
        R3, Wt2T, bt2, R2, R2, nullptr, MT, D_);
    ln2_kernel<<<dim3(MT), blk, 0, stream>>>(R2, gt, bet, out + PT_OFF, PtBf);

    // ---- q, k, v (bf16 out) ----
    gemm_bf16<false, false, false, true><<<dim3(4 * (MI / 128)), blk, 0, stream>>>(
        PiBf, WqT, bq, nullptr, nullptr, Qbf, MI, D_);
    gemm_bf16<false, false, false, true><<<dim3(4 * (MT / 128)), blk, 0, stream>>>(
        PtBf, WkT, bk, nullptr, nullptr, Kbf, MT, D_);
    gemm_bf16<false, false, false, true><<<dim3(4 * (MT / 128)), blk, 0, stream>>>(
        PtBf, WvT, bv, nullptr, nullptr, Vbf, MT, D_);

    // ---- attention: one block per batch, one wave per head ----
    attn_kernel<<<dim3(B_), blk, 0, stream>>>(Qbf, Kbf, Vbf, Obf, out + AW_OFF);

    // ---- output projection ----
    gemm_bf16<false, false, true, false><<<dim3(4 * (MI / 128)), blk, 0, stream>>>(
        Obf, WoT, bo, nullptr, out + AO_OFF, nullptr, MI, D_);

    // ---- similarity score ----
    norm_kernel<<<dim3(B_), blk, 0, stream>>>(out + AO_OFF, out + PT_OFF, n1, n2);
    score_gemm<<<dim3(8, 8), blk, 0, stream>>>(n1, n2, out + SCORE_OFF);
}

// Round 5
// 940.764 us; speedup vs baseline: 1.3556x; 1.1068x over previous
//
#include <hip/hip_runtime.h>
#include <math.h>

#define B_    512
#define SQ_   49
#define SK_   50
#define DIMG_ 2048
#define DTXT_ 768
#define D_    512
#define H_    4
#define DH_   128

// output offsets (floats): score, attn_output, attn_weights, pi, pt
#define SCORE_OFF 0
#define AO_OFF    262144      // 512*512
#define AW_OFF    13107200    // + 512*49*512
#define PI_OFF    14361600    // + 512*49*50
#define PT_OFF    27206656    // + 512*49*512

typedef unsigned short bfbits;
typedef __attribute__((ext_vector_type(8))) short short8;
typedef __attribute__((ext_vector_type(4))) float floatx4;

static __device__ __forceinline__ bfbits f2bf(float f) {
    union { float f; unsigned u; } a; a.f = f;
    return (bfbits)((a.u + 0x7fffu + ((a.u >> 16) & 1u)) >> 16);
}
static __device__ __forceinline__ float bf2f(bfbits b) {
    union { unsigned u; float f; } a; a.u = ((unsigned)b) << 16;
    return a.f;
}
static __device__ __forceinline__ float gelu_exact(float x) {
    return 0.5f * x * (1.0f + erff(x * 0.70710678118654752f));
}

// ---------------------------------------------------------------------------
// Weight transpose+cast: W (K,N) fp32 -> Wt (N,K) bf16.  K,N % 32 == 0.
// ---------------------------------------------------------------------------
__global__ __launch_bounds__(256) void wcast_t(
    const float* __restrict__ W, bfbits* __restrict__ Wt, int K, int N)
{
    __shared__ float t[32][33];
    const int k0 = blockIdx.x * 32, n0 = blockIdx.y * 32;
    const int tx = threadIdx.x & 31, ty = threadIdx.x >> 5;  // 32 x 8
    #pragma unroll
    for (int i = 0; i < 32; i += 8)
        t[ty + i][tx] = W[(size_t)(k0 + ty + i) * N + n0 + tx];
    __syncthreads();
    #pragma unroll
    for (int i = 0; i < 32; i += 8)
        Wt[(size_t)(n0 + ty + i) * K + k0 + tx] = f2bf(t[tx][ty + i]);
}

// ---------------------------------------------------------------------------
// Image transpose+cast: img[b, k, s] fp32 -> A[(b*49+s), k] bf16 (K=2048)
// block = (k-tile of 64, b)
// ---------------------------------------------------------------------------
__global__ __launch_bounds__(256) void img_t(
    const float* __restrict__ img, bfbits* __restrict__ A)
{
    __shared__ float t[64][50];
    const int b = blockIdx.y, k0 = blockIdx.x * 64;
    const float* src = img + (size_t)b * (DIMG_ * SQ_) + (size_t)k0 * SQ_;
    for (int e = threadIdx.x; e < 64 * 49; e += 256) {
        int kl = e / 49, s = e - kl * 49;
        t[kl][s] = src[kl * 49 + s];
    }
    __syncthreads();
    bfbits* dst = A + (size_t)b * SQ_ * DIMG_ + k0;
    for (int e = threadIdx.x; e < 49 * 64; e += 256) {
        int s = e >> 6, kl = e & 63;
        dst[(size_t)s * DIMG_ + kl] = f2bf(t[kl][s]);
    }
}

// ---------------------------------------------------------------------------
// Flat fp32 -> bf16 cast, 4 elements/thread. n % 4 == 0.
// ---------------------------------------------------------------------------
__global__ __launch_bounds__(256) void cast4(
    const float* __restrict__ x, bfbits* __restrict__ y, int n4)
{
    int i = blockIdx.x * 256 + threadIdx.x;
    if (i < n4) {
        float4 v = ((const float4*)x)[i];
        ushort4 u;
        u.x = f2bf(v.x); u.y = f2bf(v.y); u.z = f2bf(v.z); u.w = f2bf(v.w);
        ((ushort4*)y)[i] = u;
    }
}

// ---------------------------------------------------------------------------
// bf16 MFMA GEMM: C[M,512] = A[M,K] @ Bt[512,K]^T + bias (+res fp32).
// 256x128 tile, BK=32, 8 waves (wave grid 4Mx2N, 64x64 each, 4x4 MFMA).
// Staging ratio: 24KB per 128 wave-MFMAs (187 B/MFMA vs 256 at 128x128).
// 2-buffer counted-vmcnt pipeline (depth 2, never drain to 0 until tail):
//   wait vmcnt(3) -> barrier -> ds_read -> lgkmcnt(0) -> barrier ->
//   restage freed buffer -> MFMA (setprio).
// 1-D grid, bijective chunked XCD swizzle (nwg % 8 == 0): the 4 col-blocks
// sharing an A-panel run on one XCD (A L2-reuse).
// M%256==0, K%32==0, K>=64. res may alias Cf (elementwise read-then-write).
// GELU: Cb=gelu(v) bf16, Cf=v fp32. Else WBF: Cb=bf16(v). WF32: Cf=v.
// ---------------------------------------------------------------------------
template<bool RES, bool GELU, bool WF32, bool WBF>
__global__ __launch_bounds__(512, 4) void gemm_bf16(
    const bfbits* __restrict__ A, const bfbits* __restrict__ Bt,
    const float* __restrict__ bias, const float* res,
    float* Cf, bfbits* __restrict__ Cb, int M, int K)
{
    constexpr int N = 512;
    __shared__ __attribute__((aligned(16))) bfbits As[2][256 * 32];   // 32KB
    __shared__ __attribute__((aligned(16))) bfbits Bs[2][128 * 32];   // 16KB
    const int tid  = threadIdx.x;
    const int wave = tid >> 6, lane = tid & 63;

    // chunked XCD swizzle: o%8 = presumed XCD -> contiguous logical range
    const int nwg = gridDim.x;
    const int o = blockIdx.x;
    const int qch = nwg >> 3;                  // nwg % 8 == 0
    const int lg = (o & 7) * qch + (o >> 3);
    const int m0 = (lg >> 2) * 256, n0 = (lg & 3) * 128;

    const int wm = (wave >> 1) * 64, wn = (wave & 1) * 64;
    const int lr = lane & 15, quad = lane >> 4;

    floatx4 acc[4][4];
    #pragma unroll
    for (int i = 0; i < 4; ++i)
        #pragma unroll
        for (int j = 0; j < 4; ++j) acc[i][j] = 0.0f;

    // per-lane source row/col offset for staging (chunk c: rows c*16+(lane>>2))
    const int srow = lane >> 2;            // 0..15
    const int skof = (lane & 3) * 8;       // 0,8,16,24

    // one stage = 3 global_load_lds per wave (24 1KB chunks: 16 A + 8 B)
    auto stage = [&](int buf, int t) {
        const int k0 = t * 32;
        #pragma unroll
        for (int i = 0; i < 3; ++i) {
            const int c = wave * 3 + i;             // 0..23, uniform in wave
            if (c < 16) {
                const bfbits* ga = A + (size_t)(m0 + c * 16 + srow) * K + k0 + skof;
                __builtin_amdgcn_global_load_lds(
                    (const __attribute__((address_space(1))) void*)ga,
                    (__attribute__((address_space(3))) void*)(&As[buf][c * 512]), 16, 0, 0);
            } else {
                const bfbits* gb = Bt + (size_t)(n0 + (c - 16) * 16 + srow) * K + k0 + skof;
                __builtin_amdgcn_global_load_lds(
                    (const __attribute__((address_space(1))) void*)gb,
                    (__attribute__((address_space(3))) void*)(&Bs[buf][(c - 16) * 512]), 16, 0, 0);
            }
        }
    };

    const int nt = K >> 5;                 // >= 16 here
    stage(0, 0);
    stage(1, 1);                           // 6 loads/wave outstanding

    int cur = 0;
    for (int t = 0; t < nt; ++t) {
        // wait until stage t landed; keep stage t+1 (3 loads) in flight
        if (t + 1 < nt) asm volatile("s_waitcnt vmcnt(3)" ::: "memory");
        else            asm volatile("s_waitcnt vmcnt(0)" ::: "memory");
        __builtin_amdgcn_s_barrier();      // buf[cur] ready for all waves

        short8 af[4], bfv[4];
        #pragma unroll
        for (int i = 0; i < 4; ++i) {
            af[i]  = *(const short8*)(&As[cur][(wm + i * 16 + lr) * 32 + quad * 8]);
            bfv[i] = *(const short8*)(&Bs[cur][(wn + i * 16 + lr) * 32 + quad * 8]);
        }
        asm volatile("s_waitcnt lgkmcnt(0)" ::: "memory");
        __builtin_amdgcn_s_barrier();      // all waves done reading buf[cur]

        if (t + 2 < nt) stage(cur, t + 2); // refill freed buffer (post-barrier: safe)

        __builtin_amdgcn_s_setprio(1);
        #pragma unroll
        for (int i = 0; i < 4; ++i)
            #pragma unroll
            for (int j = 0; j < 4; ++j)
                acc[i][j] = __builtin_amdgcn_mfma_f32_16x16x32_bf16(
                    af[i], bfv[j], acc[i][j], 0, 0, 0);
        __builtin_amdgcn_s_setprio(0);

        cur ^= 1;
    }

    #pragma unroll
    for (int i = 0; i < 4; ++i) {
        #pragma unroll
        for (int j = 0; j < 4; ++j) {
            const int gc = n0 + wn + j * 16 + lr;
            const float bv = bias[gc];
            #pragma unroll
            for (int r = 0; r < 4; ++r) {
                const int gm = m0 + wm + i * 16 + quad * 4 + r;
                float v = acc[i][j][r] + bv;
                if (RES) v += res[(size_t)gm * N + gc];
                if (WF32) Cf[(size_t)gm * N + gc] = v;
                if (GELU) Cb[(size_t)gm * N + gc] = f2bf(gelu_exact(v));
                else if (WBF) Cb[(size_t)gm * N + gc] = f2bf(v);
            }
        }
    }
}

// ---------------------------------------------------------------------------
// Row LayerNorm over D=512; wave-per-row (no barriers); fp32 + bf16 out.
// grid = rows/4, block = 256 (4 waves).
// ---------------------------------------------------------------------------
__global__ __launch_bounds__(256) void ln2_kernel(
    const float* __restrict__ h, const float* __restrict__ g,
    const float* __restrict__ be, float* __restrict__ outf,
    bfbits* __restrict__ outb)
{
    const int wave = threadIdx.x >> 6, lane = threadIdx.x & 63;
    const size_t row = (size_t)blockIdx.x * 4 + wave;
    const float* hr = h + row * D_ + lane * 8;
    float4 a = *(const float4*)hr;
    float4 b = *(const float4*)(hr + 4);
    float v[8] = {a.x, a.y, a.z, a.w, b.x, b.y, b.z, b.w};

    float s = v[0] + v[1] + v[2] + v[3] + v[4] + v[5] + v[6] + v[7];
    #pragma unroll
    for (int d = 1; d < 64; d <<= 1) s += __shfl_xor(s, d);
    const float mu = s * (1.0f / 512.0f);

    float vs = 0.f;
    #pragma unroll
    for (int i = 0; i < 8; ++i) { v[i] -= mu; vs += v[i] * v[i]; }
    #pragma unroll
    for (int d = 1; d < 64; d <<= 1) vs += __shfl_xor(vs, d);
    const float sc = rsqrtf(vs * (1.0f / 512.0f) + 1e-5f);

    const float* gp = g + lane * 8;
    const float* bp = be + lane * 8;
    float4 g0 = *(const float4*)gp, g1 = *(const float4*)(gp + 4);
    float4 b0 = *(const float4*)bp, b1 = *(const float4*)(bp + 4);
    float gg[8] = {g0.x, g0.y, g0.z, g0.w, g1.x, g1.y, g1.z, g1.w};
    float bb[8] = {b0.x, b0.y, b0.z, b0.w, b1.x, b1.y, b1.z, b1.w};

    float o[8];
    short8 ob;
    #pragma unroll
    for (int i = 0; i < 8; ++i) {
        o[i] = gg[i] * v[i] * sc + bb[i];
        ob[i] = (short)f2bf(o[i]);
    }
    float* of = outf + row * D_ + lane * 8;
    *(float4*)of       = make_float4(o[0], o[1], o[2], o[3]);
    *(float4*)(of + 4) = make_float4(o[4], o[5], o[6], o[7]);
    *(short8*)(outb + row * D_ + lane * 8) = ob;
}

// ---------------------------------------------------------------------------
// Fused attention: one block per batch b, one wave per head.
// QK^T via MFMA computing S^T[ki][qi] = sum_d K[ki][d]*Q[qi][d]  (both row
// reads). Softmax over ki is lane-local(16 vals)+shfl_xor(16,32). P (fp32)
// goes to LDS; aw computed in-block; PV stays scalar (V reads coalesced).
// Padded tiles (49->64, 50->64) read workspace slack, masked to -inf / cut.
// ---------------------------------------------------------------------------
__global__ __launch_bounds__(256) void attn_kernel(
    const bfbits* __restrict__ q, const bfbits* __restrict__ k,
    const bfbits* __restrict__ v, bfbits* __restrict__ o,
    float* __restrict__ aw)
{
    constexpr int ROWF = 69;               // fp32 row stride (banks: 5*qi%32)
    __shared__ float sc[H_][SQ_ * ROWF];   // 54,096 B total
    const int b = blockIdx.x;
    const int tid = threadIdx.x;
    const int h = tid >> 6, lane = tid & 63;
    const int lr = lane & 15, g = lane >> 4;

    const bfbits* kb = k + ((size_t)b * SK_) * D_ + h * DH_;
    const bfbits* qb = q + ((size_t)b * SQ_) * D_ + h * DH_;

    // ---- S^T = K @ Q^T  (64x64 padded, 16 tiles, K-dim 128 = 4 steps) ----
    floatx4 acc[4][4];
    #pragma unroll
    for (int mi = 0; mi < 4; ++mi)
        #pragma unroll
        for (int ni = 0; ni < 4; ++ni) acc[mi][ni] = 0.0f;

    #pragma unroll
    for (int ks = 0; ks < 4; ++ks) {
        short8 afr[4], bfr[4];
        #pragma unroll
        for (int mi = 0; mi < 4; ++mi)
            afr[mi] = *(const short8*)(kb + (size_t)(mi * 16 + lr) * D_ + ks * 32 + g * 8);
        #pragma unroll
        for (int ni = 0; ni < 4; ++ni)
            bfr[ni] = *(const short8*)(qb + (size_t)(ni * 16 + lr) * D_ + ks * 32 + g * 8);
        #pragma unroll
        for (int mi = 0; mi < 4; ++mi)
            #pragma unroll
            for (int ni = 0; ni < 4; ++ni)
                acc[mi][ni] = __builtin_amdgcn_mfma_f32_16x16x32_bf16(
                    afr[mi], bfr[ni], acc[mi][ni], 0, 0, 0);
    }

    // ---- softmax over ki (rows of S^T) per qi column; write P to LDS ----
    const float scale = 0.08838834764831845f;   // 1/sqrt(128)
    #pragma unroll
    for (int ni = 0; ni < 4; ++ni) {
        const int qi = ni * 16 + lr;
        float mx = -1e30f;
        #pragma unroll
        for (int mi = 0; mi < 4; ++mi)
            #pragma unroll
            for (int r = 0; r < 4; ++r) {
                const int ki = mi * 16 + g * 4 + r;
                float s = (ki < SK_) ? acc[mi][ni][r] * scale : -1e30f;
                acc[mi][ni][r] = s;
                mx = fmaxf(mx, s);
            }
        mx = fmaxf(mx, __shfl_xor(mx, 16));
        mx = fmaxf(mx, __shfl_xor(mx, 32));
        float sum = 0.f;
        #pragma unroll
        for (int mi = 0; mi < 4; ++mi)
            #pragma unroll
            for (int r = 0; r < 4; ++r) {
                float ev = __expf(acc[mi][ni][r] - mx);  // masked -> exp(-inf)=0
                acc[mi][ni][r] = ev;
                sum += ev;
            }
        sum += __shfl_xor(sum, 16);
        sum += __shfl_xor(sum, 32);
        const float inv = 1.0f / sum;
        if (qi < SQ_) {
            #pragma unroll
            for (int mi = 0; mi < 4; ++mi) {
                float4 w;
                w.x = acc[mi][ni][0] * inv;
                w.y = acc[mi][ni][1] * inv;
                w.z = acc[mi][ni][2] * inv;
                w.w = acc[mi][ni][3] * inv;
                *(float4*)&sc[h][qi * ROWF + mi * 16 + g * 4] = w;
            }
        }
    }
    __syncthreads();

    // ---- aw[b,qi,ki] = 0.25 * sum_h P ----
    for (int e = tid; e < SQ_ * SK_; e += 256) {
        int qi = e / SK_, ki = e - qi * SK_;
        const int off = qi * ROWF + ki;
        aw[(size_t)b * (SQ_ * SK_) + e] =
            0.25f * (sc[0][off] + sc[1][off] + sc[2][off] + sc[3][off]);
    }

    // ---- PV: scalar fp32, V reads coalesced (L1/L2 resident) ----
    const bfbits* vb = v + ((size_t)b * SK_) * D_ + h * DH_;
    bfbits* ob = o + ((size_t)b * SQ_) * D_ + h * DH_;
    for (int e = lane; e < SQ_ * 16; e += 64) {
        const int qi = e >> 4, dc = e & 15;      // 8 d-elems per chunk
        const float* sr = &sc[h][qi * ROWF];
        float s[8] = {0.f, 0.f, 0.f, 0.f, 0.f, 0.f, 0.f, 0.f};
        for (int ki = 0; ki < SK_; ++ki) {
            const float a = sr[ki];
            short8 u = *(const short8*)(vb + (size_t)ki * D_ + dc * 8);
            #pragma unroll
            for (int j = 0; j < 8; ++j)
                s[j] = fmaf(a, bf2f((bfbits)u[j]), s[j]);
        }
        short8 ov;
        #pragma unroll
        for (int j = 0; j < 8; ++j) ov[j] = (short)f2bf(s[j]);
        *(short8*)(ob + (size_t)qi * D_ + dc * 8) = ov;
    }
}

// ---------------------------------------------------------------------------
// avg_attn -> n1; cls -> n2 (fp32)
// ---------------------------------------------------------------------------
__global__ __launch_bounds__(256) void norm_kernel(
    const float* __restrict__ ao, const float* __restrict__ pt,
    float* __restrict__ n1, float* __restrict__ n2)
{
    __shared__ float red[256];
    const int b = blockIdx.x, tid = threadIdx.x;
    float s0 = 0.f, s1 = 0.f;
    for (int s = 0; s < SQ_; ++s) {
        s0 += ao[((size_t)(b * SQ_ + s)) * D_ + tid];
        s1 += ao[((size_t)(b * SQ_ + s)) * D_ + 256 + tid];
    }
    s0 *= (1.0f / 49.0f);
    s1 *= (1.0f / 49.0f);
    red[tid] = s0 * s0 + s1 * s1;
    __syncthreads();
    for (int st = 128; st > 0; st >>= 1) {
        if (tid < st) red[tid] += red[tid + st];
        __syncthreads();
    }
    float inv = rsqrtf(red[0]);
    __syncthreads();
    n1[(size_t)b * D_ + tid] = s0 * inv;
    n1[(size_t)b * D_ + 256 + tid] = s1 * inv;

    float c0 = pt[((size_t)(b * SK_)) * D_ + tid];
    float c1 = pt[((size_t)(b * SK_)) * D_ + 256 + tid];
    red[tid] = c0 * c0 + c1 * c1;
    __syncthreads();
    for (int st = 128; st > 0; st >>= 1) {
        if (tid < st) red[tid] += red[tid + st];
        __syncthreads();
    }
    float inv2 = rsqrtf(red[0]);
    n2[(size_t)b * D_ + tid] = c0 * inv2;
    n2[(size_t)b * D_ + 256 + tid] = c1 * inv2;
}

// ---------------------------------------------------------------------------
// fp32 score GEMM: C[512,512] = n1[512,512] @ n2[512,512]^T  (tiny)
// ---------------------------------------------------------------------------
__global__ __launch_bounds__(256) void score_gemm(
    const float* __restrict__ A, const float* __restrict__ Bm,
    float* __restrict__ C)
{
    const int BM = 64, BN = 64, BK = 16, Kt = 512, Nt = 512;
    __shared__ float As[BK][BM + 1];
    __shared__ float Bs[BK][BN + 1];
    const int tid = threadIdx.x;
    const int m0 = blockIdx.y * BM, n0 = blockIdx.x * BN;
    const int tc = tid & 15, tr = tid >> 4;
    float acc[4][4] = {};
    for (int k0 = 0; k0 < Kt; k0 += BK) {
        #pragma unroll
        for (int i = 0; i < 4; ++i) {
            int idx = tid + i * 256;
            int m = idx >> 4, kk = idx & 15;
            As[kk][m] = A[(size_t)(m0 + m) * Kt + k0 + kk];
            Bs[kk][m] = Bm[(size_t)(n0 + m) * Kt + k0 + kk];
        }
        __syncthreads();
        #pragma unroll
        for (int kk = 0; kk < BK; ++kk) {
            float a4[4], b4[4];
            #pragma unroll
            for (int i = 0; i < 4; ++i) a4[i] = As[kk][tr * 4 + i];
            #pragma unroll
            for (int j = 0; j < 4; ++j) b4[j] = Bs[kk][tc * 4 + j];
            #pragma unroll
            for (int i = 0; i < 4; ++i)
                #pragma unroll
                for (int j = 0; j < 4; ++j)
                    acc[i][j] = fmaf(a4[i], b4[j], acc[i][j]);
        }
        __syncthreads();
    }
    #pragma unroll
    for (int i = 0; i < 4; ++i)
        #pragma unroll
        for (int j = 0; j < 4; ++j)
            C[(size_t)(m0 + tr * 4 + i) * Nt + n0 + tc * 4 + j] = acc[i][j];
}

extern "C" void kernel_launch(void* const* d_in, const int* in_sizes, int n_in,
                              void* d_out, int out_size, void* d_ws, size_t ws_size,
                              hipStream_t stream)
{
    const float* img = (const float*)d_in[0];
    const float* txt = (const float*)d_in[1];
    const float* Wi1 = (const float*)d_in[2];  const float* bi1 = (const float*)d_in[3];
    const float* Wi2 = (const float*)d_in[4];  const float* bi2 = (const float*)d_in[5];
    const float* gi  = (const float*)d_in[6];  const float* bei = (const float*)d_in[7];
    const float* Wt1 = (const float*)d_in[8];  const float* bt1 = (const float*)d_in[9];
    const float* Wt2 = (const float*)d_in[10]; const float* bt2 = (const float*)d_in[11];
    const float* gt  = (const float*)d_in[12]; const float* bet = (const float*)d_in[13];
    const float* Wq  = (const float*)d_in[14]; const float* bq  = (const float*)d_in[15];
    const float* Wk  = (const float*)d_in[16]; const float* bk  = (const float*)d_in[17];
    const float* Wv  = (const float*)d_in[18]; const float* bv  = (const float*)d_in[19];
    const float* Wo  = (const float*)d_in[20]; const float* bo  = (const float*)d_in[21];
    float* out = (float*)d_out;

    // ---- workspace layout (~230 MiB) ----
    bfbits* Wi1T = (bfbits*)d_ws;                 // 2048*512
    bfbits* Wi2T = Wi1T + 1048576;                // 512*512
    bfbits* Wt1T = Wi2T + 262144;                 // 768*512
    bfbits* Wt2T = Wt1T + 393216;
    bfbits* WqT  = Wt2T + 262144;
    bfbits* WkT  = WqT  + 262144;
    bfbits* WvT  = WkT  + 262144;
    bfbits* WoT  = WvT  + 262144;
    bfbits* R1   = WoT  + 262144;                 // 51,380,224 bf16 elems
    bfbits* Aimg = R1;                            // 25088*2048
    bfbits* Atxt = R1;                            // 25600*768 (after img phase)
    bfbits* Qbf  = R1 + 20000000;                 // 25088*512
    bfbits* Kbf  = R1 + 33200000;                 // 25600*512
    float*  R2   = (float*)(R1 + 51380224);       // 13,107,200 floats (P/H)
    bfbits* Vbf  = (bfbits*)R2;                   // 25600*512 (after H dead)
    bfbits* R3   = (bfbits*)(R2 + 13107200);      // 13,107,200 bf16 (G / Obf)
    bfbits* Obf  = R3;
    bfbits* PiBf = R3 + 13107200;                 // 25088*512
    bfbits* PtBf = PiBf + 12845056;               // 25600*512
    float*  n1   = (float*)(PtBf + 13107200);
    float*  n2   = n1 + 262144;

    const int MI = B_ * SQ_;   // 25088
    const int MT = B_ * SK_;   // 25600
    dim3 blk(256);
    dim3 blk512(512);

    // weights -> transposed bf16
    wcast_t<<<dim3(DIMG_ / 32, D_ / 32), blk, 0, stream>>>(Wi1, Wi1T, DIMG_, D_);
    wcast_t<<<dim3(D_ / 32, D_ / 32),    blk, 0, stream>>>(Wi2, Wi2T, D_, D_);
    wcast_t<<<dim3(DTXT_ / 32, D_ / 32), blk, 0, stream>>>(Wt1, Wt1T, DTXT_, D_);
    wcast_t<<<dim3(D_ / 32, D_ / 32),    blk, 0, stream>>>(Wt2, Wt2T, D_, D_);
    wcast_t<<<dim3(D_ / 32, D_ / 32),    blk, 0, stream>>>(Wq, WqT, D_, D_);
    wcast_t<<<dim3(D_ / 32, D_ / 32),    blk, 0, stream>>>(Wk, WkT, D_, D_);
    wcast_t<<<dim3(D_ / 32, D_ / 32),    blk, 0, stream>>>(Wv, WvT, D_, D_);
    wcast_t<<<dim3(D_ / 32, D_ / 32),    blk, 0, stream>>>(Wo, WoT, D_, D_);

    // ---- image head ----  (1-D grids: nwg = 4 * M/256, all % 8 == 0)
    img_t<<<dim3(DIMG_ / 64, B_), blk, 0, stream>>>(img, Aimg);
    gemm_bf16<false, true, true, true><<<dim3(4 * (MI / 256)), blk512, 0, stream>>>(
        Aimg, Wi1T, bi1, nullptr, R2, R3, MI, DIMG_);            // p fp32 + gelu bf16
    gemm_bf16<true, false, true, false><<<dim3(4 * (MI / 256)), blk512, 0, stream>>>(
        R3, Wi2T, bi2, R2, R2, nullptr, MI, D_);                 // h = g@W2+b2+p (in-place)
    ln2_kernel<<<dim3(MI / 4), blk, 0, stream>>>(R2, gi, bei, out + PI_OFF, PiBf);

    // ---- text head ----
    cast4<<<dim3((MT * DTXT_ / 4 + 255) / 256), blk, 0, stream>>>(txt, Atxt, MT * DTXT_ / 4);
    gemm_bf16<false, true, true, true><<<dim3(4 * (MT / 256)), blk512, 0, stream>>>(
        Atxt, Wt1T, bt1, nullptr, R2, R3, MT, DTXT_);
    gemm_bf16<true, false, true, false><<<dim3(4 * (MT / 256)), blk512, 0, stream>>>(
        R3, Wt2T, bt2, R2, R2, nullptr, MT, D_);
    ln2_kernel<<<dim3(MT / 4), blk, 0, stream>>>(R2, gt, bet, out + PT_OFF, PtBf);

    // ---- q, k, v (bf16 out) ----
    gemm_bf16<false, false, false, true><<<dim3(4 * (MI / 256)), blk512, 0, stream>>>(
        PiBf, WqT, bq, nullptr, nullptr, Qbf, MI, D_);
    gemm_bf16<false, false, false, true><<<dim3(4 * (MT / 256)), blk512, 0, stream>>>(
        PtBf, WkT, bk, nullptr, nullptr, Kbf, MT, D_);
    gemm_bf16<false, false, false, true><<<dim3(4 * (MT / 256)), blk512, 0, stream>>>(
        PtBf, WvT, bv, nullptr, nullptr, Vbf, MT, D_);

    // ---- attention: one block per batch, one wave per head ----
    attn_kernel<<<dim3(B_), blk, 0, stream>>>(Qbf, Kbf, Vbf, Obf, out + AW_OFF);

    // ---- output projection ----
    gemm_bf16<false, false, true, false><<<dim3(4 * (MI / 256)), blk512, 0, stream>>>(
        Obf, WoT, bo, nullptr, out + AO_OFF, nullptr, MI, D_);

    // ---- similarity score ----
    norm_kernel<<<dim3(B_), blk, 0, stream>>>(out + AO_OFF, out + PT_OFF, n1, n2);
    score_gemm<<<dim3(8, 8), blk, 0, stream>>>(n1, n2, out + SCORE_OFF);
}